// Round 4
// baseline (342.720 us; speedup 1.0000x reference)
//
#include <hip/hip_runtime.h>
#include <stdint.h>

#define BB 8
#define NN 4096
#define MM 1366   // len(arange(0,4096,3))
#define NS 32
#define RAD2 0.01f
#define NGRP 64          // groups of 64 sorted points per batch
#define KW 8             // waves per k_knn block

__device__ __forceinline__ float rl(float v, int l) {
    return __int_as_float(__builtin_amdgcn_readlane(__float_as_int(v), l));
}
__device__ __forceinline__ uint32_t um(uint32_t a, uint32_t b) { return a < b ? a : b; }
__device__ __forceinline__ uint32_t ux(uint32_t a, uint32_t b) { return a > b ? a : b; }
__device__ __forceinline__ uint32_t um3(uint32_t a, uint32_t b, uint32_t c) { return um(um(a, b), c); }

// merge sorted pair (s0<=s1) into sorted-10 kk
__device__ __forceinline__ void mrg2(uint32_t* kk, uint32_t s0, uint32_t s1) {
    uint32_t n0 = um(kk[0], s0);
    uint32_t n1 = um3(kk[1], ux(kk[0], s0), s1);
    uint32_t n2 = um3(kk[2], ux(kk[1], s0), ux(kk[0], s1));
    uint32_t n3 = um3(kk[3], ux(kk[2], s0), ux(kk[1], s1));
    uint32_t n4 = um3(kk[4], ux(kk[3], s0), ux(kk[2], s1));
    uint32_t n5 = um3(kk[5], ux(kk[4], s0), ux(kk[3], s1));
    uint32_t n6 = um3(kk[6], ux(kk[5], s0), ux(kk[4], s1));
    uint32_t n7 = um3(kk[7], ux(kk[6], s0), ux(kk[5], s1));
    uint32_t n8 = um3(kk[8], ux(kk[7], s0), ux(kk[6], s1));
    uint32_t n9 = um3(kk[9], ux(kk[8], s0), ux(kk[7], s1));
    kk[0]=n0; kk[1]=n1; kk[2]=n2; kk[3]=n3; kk[4]=n4;
    kk[5]=n5; kk[6]=n6; kk[7]=n7; kk[8]=n8; kk[9]=n9;
}

// merge sorted quad (s0<=s1<=s2<=s3) into sorted-10 kk
__device__ __forceinline__ void mrg4(uint32_t* kk, uint32_t s0, uint32_t s1,
                                     uint32_t s2, uint32_t s3) {
    uint32_t n0 = um(kk[0], s0);
    uint32_t n1 = um3(kk[1], ux(kk[0], s0), s1);
    uint32_t n2 = um(um3(kk[2], ux(kk[1], s0), ux(kk[0], s1)), s2);
    uint32_t n3 = um3(um3(kk[3], ux(kk[2], s0), ux(kk[1], s1)), ux(kk[0], s2), s3);
    uint32_t n4 = um3(um3(kk[4], ux(kk[3], s0), ux(kk[2], s1)), ux(kk[1], s2), ux(kk[0], s3));
    uint32_t n5 = um3(um3(kk[5], ux(kk[4], s0), ux(kk[3], s1)), ux(kk[2], s2), ux(kk[1], s3));
    uint32_t n6 = um3(um3(kk[6], ux(kk[5], s0), ux(kk[4], s1)), ux(kk[3], s2), ux(kk[2], s3));
    uint32_t n7 = um3(um3(kk[7], ux(kk[6], s0), ux(kk[5], s1)), ux(kk[4], s2), ux(kk[3], s3));
    uint32_t n8 = um3(um3(kk[8], ux(kk[7], s0), ux(kk[6], s1)), ux(kk[5], s2), ux(kk[4], s3));
    uint32_t n9 = um3(um3(kk[9], ux(kk[8], s0), ux(kk[7], s1)), ux(kk[6], s2), ux(kk[5], s3));
    kk[0]=n0; kk[1]=n1; kk[2]=n2; kk[3]=n3; kk[4]=n4;
    kk[5]=n5; kk[6]=n6; kk[7]=n7; kk[8]=n8; kk[9]=n9;
}

// sort 4 keys ascending: 5-CE network
__device__ __forceinline__ void srt4(uint32_t& a, uint32_t& b, uint32_t& c, uint32_t& d) {
    uint32_t t0 = um(a, b), t1 = ux(a, b), t2 = um(c, d), t3 = ux(c, d);
    uint32_t s0 = um(t0, t2), m0 = ux(t0, t2), m1 = um(t1, t3), s3 = ux(t1, t3);
    a = s0; b = um(m0, m1); c = ux(m0, m1); d = s3;
}

// spread 4 bits to every 3rd bit position (0,3,6,9)
__device__ __forceinline__ uint32_t spr3(uint32_t v) {
    v = (v | (v << 4)) & 0xC3u;
    v = (v | (v << 2)) & 0x249u;
    return v;
}

// ---------------- K1: stem (+ prep absorbed as extra blocks) ----------------
__global__ __launch_bounds__(256) void k_stem(const float* __restrict__ data,
                                              const float* __restrict__ Ws,
                                              const float* __restrict__ bs,
                                              float* __restrict__ f0,
                                              float* __restrict__ out,
                                              float4* __restrict__ cand4) {
    int blk = blockIdx.x;
    if (blk >= (BB * NN * 64) / 256) {
        // prep blocks: copy data -> out, build cand4 = (x,y,z,|p|^2)
        int t = (blk - (BB * NN * 64) / 256) * 256 + threadIdx.x;   // BB*NN
        float x = data[t * 3], y = data[t * 3 + 1], z = data[t * 3 + 2];
        out[t * 3] = x; out[t * 3 + 1] = y; out[t * 3 + 2] = z;
        cand4[t] = make_float4(x, y, z, x * x + y * y + z * z);
        return;
    }
    int t = blk * 256 + threadIdx.x;
    int c = t & 63;
    int r = t >> 6;
    const float* d = data + r * 3;
    float acc = bs[c];
    acc = fmaf(d[0], Ws[c], acc);
    acc = fmaf(d[1], Ws[64 + c], acc);
    acc = fmaf(d[2], Ws[128 + c], acc);
    f0[t] = fmaxf(acc, 0.f);
}

// ---------------- K1b: Morton counting-sort of each batch + per-group bboxes ----------------
__global__ __launch_bounds__(256) void k_sort(const float4* __restrict__ cand4,
                                              float4* __restrict__ cand4s,
                                              uint32_t* __restrict__ perm,
                                              float4* __restrict__ gbox) {
    __shared__ uint32_t cnt[4096];   // 16^3 Morton cells
    __shared__ uint32_t part[256];
    int b = blockIdx.x, t = threadIdx.x;
    const float4* cb = cand4 + b * NN;
    for (int i = t; i < 4096; i += 256) cnt[i] = 0;
    __syncthreads();
    uint32_t cid[16];
    #pragma unroll
    for (int u = 0; u < 16; ++u) {
        float4 c = cb[u * 256 + t];
        int ix = (int)floorf((c.x + 4.f) * 2.f);
        int iy = (int)floorf((c.y + 4.f) * 2.f);
        int iz = (int)floorf((c.z + 4.f) * 2.f);
        ix = ix < 0 ? 0 : (ix > 15 ? 15 : ix);
        iy = iy < 0 ? 0 : (iy > 15 ? 15 : iy);
        iz = iz < 0 ? 0 : (iz > 15 ? 15 : iz);
        uint32_t m = spr3((uint32_t)ix) | (spr3((uint32_t)iy) << 1) | (spr3((uint32_t)iz) << 2);
        cid[u] = m;
        atomicAdd(&cnt[m], 1u);
    }
    __syncthreads();
    // prefix sum over 4096 bins: 16 serial per thread + block scan of 256
    uint32_t c16[16];
    uint32_t s = 0;
    #pragma unroll
    for (int u = 0; u < 16; ++u) { c16[u] = cnt[t * 16 + u]; s += c16[u]; }
    part[t] = s;
    __syncthreads();
    for (int off = 1; off < 256; off <<= 1) {
        uint32_t v = (t >= off) ? part[t - off] : 0u;
        __syncthreads();
        part[t] += v;
        __syncthreads();
    }
    uint32_t run = part[t] - s;   // exclusive prefix of this thread's 16 bins
    #pragma unroll
    for (int u = 0; u < 16; ++u) { cnt[t * 16 + u] = run; run += c16[u]; }
    __syncthreads();
    // scatter (order within cell irrelevant: selection later is an exact total order)
    #pragma unroll
    for (int u = 0; u < 16; ++u) {
        int p = u * 256 + t;
        uint32_t pos = atomicAdd(&cnt[cid[u]], 1u);
        cand4s[b * NN + pos] = cb[p];
        perm[b * NN + pos] = (uint32_t)p;   // 12-bit local original index
    }
    __syncthreads();   // drains vmcnt: our global writes are visible to our reads below
    // per-group (64 sorted points) bounding boxes
    if (t < NGRP) {
        float4 mn = make_float4(1e30f, 1e30f, 1e30f, 0.f);
        float4 mx = make_float4(-1e30f, -1e30f, -1e30f, 0.f);
        for (int j = 0; j < 64; ++j) {
            float4 c = cand4s[b * NN + t * 64 + j];
            mn.x = fminf(mn.x, c.x); mn.y = fminf(mn.y, c.y); mn.z = fminf(mn.z, c.z);
            mx.x = fmaxf(mx.x, c.x); mx.y = fmaxf(mx.y, c.y); mx.z = fmaxf(mx.z, c.z);
        }
        gbox[(b * NGRP + t) * 2]     = mn;
        gbox[(b * NGRP + t) * 2 + 1] = mx;
    }
}

// ---------------- K2: exact top-10 NN, batched nearest-16 + single merge ----------------
// 8 waves per group, disjoint partials. All waves redundantly run the deterministic
// greedy nearest-box extraction (cheap shfl argmin) so there is NO per-round barrier:
// wave w scans own-group packets {2w,2w+1} plus extracted ranks {w, w+8}. One
// publish+merge (wave0) gives the combined top-10; terminate iff min remaining box
// distance >= combined ub (monotone order). Rare extension rounds handle the rest.
// Exactness: a skipped/pruned group has bd >= ub >= (partial or combined) 10th true
// distance, so none of its points can enter the final merged top-10 (unique keys).
__global__ __launch_bounds__(512) void k_knn(const float4* __restrict__ cand4s,
                                             const uint32_t* __restrict__ perm,
                                             const float4* __restrict__ gbox,
                                             uint32_t* __restrict__ mrg) {
    __shared__ float4 sBox[2 * NGRP];
    __shared__ uint32_t sKK[KW][64][10];
    __shared__ uint32_t sThr[64];
    __shared__ float sUb;
    __shared__ int sN;
    int t = threadIdx.x, w = t >> 6, lane = t & 63;
    int gw = blockIdx.x;           // global group id 0..511
    int b = gw >> 6;
    int g = gw & (NGRP - 1);
    for (int i = t; i < 2 * NGRP; i += 512) sBox[i] = gbox[b * 2 * NGRP + i];
    __syncthreads();
    const float4* cs = cand4s + b * NN;
    const uint32_t* ps = perm + b * NN;
    float4 me = cs[g * 64 + lane];
    uint32_t mo = ps[g * 64 + lane];
    float px = me.x, py = me.y, pz = me.z, pa = me.w;
    uint32_t kk[10];
    #pragma unroll
    for (int r = 0; r < 10; ++r) kk[r] = 0xFFFFFF00u + r;   // ascending sentinels

    auto scan_packets = [&](int jg, int j0, int j1, uint32_t thrC) {
        const float4* cp = cs + jg * 64;
        const uint4* pq = (const uint4*)(ps + jg * 64);
        uint32_t thr = um(kk[9], thrC);
        for (int j = j0; j < j1; ++j) {
            float4 ca  = cp[j * 4];
            float4 cbv = cp[j * 4 + 1];
            float4 cc  = cp[j * 4 + 2];
            float4 cd  = cp[j * 4 + 3];
            uint4 pm = pq[j];
            float da  = fmaxf(fmaf(-2.f, fmaf(pz, ca.z,  fmaf(py, ca.y,  px * ca.x)),  pa + ca.w),  0.f);
            float db_ = fmaxf(fmaf(-2.f, fmaf(pz, cbv.z, fmaf(py, cbv.y, px * cbv.x)), pa + cbv.w), 0.f);
            float dc  = fmaxf(fmaf(-2.f, fmaf(pz, cc.z,  fmaf(py, cc.y,  px * cc.x)),  pa + cc.w),  0.f);
            float dd  = fmaxf(fmaf(-2.f, fmaf(pz, cd.z,  fmaf(py, cd.y,  px * cd.x)),  pa + cd.w),  0.f);
            uint32_t ka = (__float_as_uint(da)  & 0xFFFFF000u) | pm.x;
            uint32_t kb = (__float_as_uint(db_) & 0xFFFFF000u) | pm.y;
            uint32_t kc = (__float_as_uint(dc)  & 0xFFFFF000u) | pm.z;
            uint32_t kd = (__float_as_uint(dd)  & 0xFFFFF000u) | pm.w;
            uint32_t mn4 = um(um(ka, kb), um(kc, kd));
            if (__ballot(mn4 < thr)) {       // wave-uniform: skip if nobody can improve
                srt4(ka, kb, kc, kd);
                mrg4(kk, ka, kb, kc, kd);
                thr = um(kk[9], thrC);
            }
        }
    };
    auto bound = [&]() {
        // wave-max upper bound of true d2 of kk[9] (+1 ulp at 20-bit granularity)
        uint32_t kb9 = kk[9] & 0xFFFFF000u;
        float u2 = (kb9 >= 0x7F000000u) ? 1e30f : __uint_as_float(kb9 + 0x1000u);
        #pragma unroll
        for (int off = 1; off < 64; off <<= 1) u2 = fmaxf(u2, __shfl_xor(u2, off));
        return u2;
    };

    // box distance of every other group (lane j <-> group j); identical in all waves
    float bdj;
    {
        float4 amn = sBox[g * 2], amx = sBox[g * 2 + 1];
        float4 bmn = sBox[lane * 2], bmx = sBox[lane * 2 + 1];
        float bx = fmaxf(fmaxf(amn.x - bmx.x, bmn.x - amx.x), 0.f);
        float by = fmaxf(fmaxf(amn.y - bmx.y, bmn.y - amx.y), 0.f);
        float bz = fmaxf(fmaxf(amn.z - bmx.z, bmn.z - amx.z), 0.f);
        bdj = fmaf(bx, bx, fmaf(by, by, bz * bz));
        if (lane == g) bdj = 1e30f;          // own group handled by the seed
    }

    scan_packets(g, w * 2, w * 2 + 2, 0xFFFFFFFFu);   // disjoint own-group seed

    // extract the 16 nearest groups (deterministic, redundant in all waves);
    // wave w owns ranks w and w+8
    int g0 = 0, g1 = 0;
    float bd1 = 1e30f;
    for (int i = 0; i < 16; ++i) {
        float mind = bdj;
        #pragma unroll
        for (int off = 1; off < 64; off <<= 1) mind = fminf(mind, __shfl_xor(mind, off));
        unsigned long long mm = __ballot(bdj == mind);
        int jl = (int)__builtin_ctzll(mm);
        if (i == w) g0 = jl;
        if (i == w + 8) { g1 = jl; bd1 = mind; }
        if (lane == jl) bdj = 1e30f;
    }
    scan_packets(g0, 0, 16, 0xFFFFFFFFu);
    if (bd1 < bound() * 1.0005f)             // own-partial prune of the far rank (exact)
        scan_packets(g1, 0, 16, 0xFFFFFFFFu);

    int rb = 16;
    uint32_t tmp[10];
    while (true) {
        #pragma unroll
        for (int r = 0; r < 10; ++r) sKK[w][lane][r] = kk[r];
        __syncthreads();
        if (w == 0) {
            #pragma unroll
            for (int r = 0; r < 10; ++r) tmp[r] = kk[r];
            for (int ww = 1; ww < KW; ++ww) {
                uint32_t s[10];
                #pragma unroll
                for (int r = 0; r < 10; ++r) s[r] = sKK[ww][lane][r];
                mrg4(tmp, s[0], s[1], s[2], s[3]);
                mrg4(tmp, s[4], s[5], s[6], s[7]);
                mrg2(tmp, s[8], s[9]);
            }
            sThr[lane] = tmp[9];
            uint32_t kb9 = tmp[9] & 0xFFFFF000u;
            float u2 = (kb9 >= 0x7F000000u) ? 1e30f : __uint_as_float(kb9 + 0x1000u);
            #pragma unroll
            for (int off = 1; off < 64; off <<= 1) u2 = fmaxf(u2, __shfl_xor(u2, off));
            float ubt = u2 * 1.0005f;
            float mind = bdj;                // min remaining box distance (sorted order)
            #pragma unroll
            for (int off = 1; off < 64; off <<= 1) mind = fminf(mind, __shfl_xor(mind, off));
            int n = 0;
            if (rb < NGRP - 1 && mind < ubt)
                n = (NGRP - 1 - rb) < KW ? (NGRP - 1 - rb) : KW;
            if (lane == 0) { sN = n; sUb = ubt; }
        }
        __syncthreads();
        int n = sN;
        if (n == 0) break;                   // tmp (wave0) is the final combined top-10
        float ubt = sUb;
        uint32_t thrC = sThr[lane];
        int eg = -1; float ebd = 1e30f;
        for (int i = 0; i < n; ++i) {        // all waves extract identically
            float mind = bdj;
            #pragma unroll
            for (int off = 1; off < 64; off <<= 1) mind = fminf(mind, __shfl_xor(mind, off));
            unsigned long long mm = __ballot(bdj == mind);
            int jl = (int)__builtin_ctzll(mm);
            if (i == w) { eg = jl; ebd = mind; }
            if (lane == jl) bdj = 1e30f;
        }
        if (w < n && ebd < ubt)              // per-wave prune vs combined ub (exact)
            scan_packets(eg, 0, 16, thrC);
        rb += n;
    }
    if (w == 0) {
        int gp = b * NN + (int)mo;
        #pragma unroll
        for (int r = 0; r < 10; ++r) mrg[r * (BB * NN) + gp] = tmp[r];
    }
}

// ---------------- K2b: cov, Jacobi eig, eig-MLP from merged 10-NN ----------------
__device__ __forceinline__ void jrot(float& app, float& aqq, float& apq,
                                     float& arp, float& arq) {
    float ap = apq;
    if (fabsf(ap) > 1e-32f) {
        float th = (aqq - app) / (2.f * ap);
        float t = 1.f / (fabsf(th) + sqrtf(th * th + 1.f));
        t = th < 0.f ? -t : t;
        float c = 1.f / sqrtf(t * t + 1.f);
        float s = t * c;
        app = app - t * ap;
        aqq = aqq + t * ap;
        apq = 0.f;
        float rp = arp, rq = arq;
        arp = c * rp - s * rq;
        arq = s * rp + c * rq;
    }
}

__global__ __launch_bounds__(256) void k_knn_eig(const float4* __restrict__ cand4,
                                                 const uint32_t* __restrict__ mrg,
                                                 const float* __restrict__ We1,
                                                 const float* __restrict__ be1,
                                                 const float* __restrict__ We2,
                                                 const float* __restrict__ be2,
                                                 float* __restrict__ ef) {
    int t = blockIdx.x * 256 + threadIdx.x;   // B*N
    int b = t >> 12;
    const float4* cb = cand4 + b * NN;
    uint32_t kk[10];
    #pragma unroll
    for (int r = 0; r < 10; ++r) kk[r] = mrg[r * (BB * NN) + t];
    float xs[10], ys[10], zs[10];
    float mx = 0.f, my = 0.f, mz = 0.f;
    #pragma unroll
    for (int r = 0; r < 10; ++r) {
        int n = (int)(kk[r] & 0xFFFu);
        float4 cr = cb[n];
        xs[r] = cr.x; ys[r] = cr.y; zs[r] = cr.z;
        mx += xs[r]; my += ys[r]; mz += zs[r];
    }
    mx *= 0.1f; my *= 0.1f; mz *= 0.1f;
    float a00 = 0, a01 = 0, a02 = 0, a11 = 0, a12 = 0, a22 = 0;
    #pragma unroll
    for (int r = 0; r < 10; ++r) {
        float x = xs[r] - mx, y = ys[r] - my, z = zs[r] - mz;
        a00 = fmaf(x, x, a00); a01 = fmaf(x, y, a01); a02 = fmaf(x, z, a02);
        a11 = fmaf(y, y, a11); a12 = fmaf(y, z, a12); a22 = fmaf(z, z, a22);
    }
    a00 *= 0.1f; a01 *= 0.1f; a02 *= 0.1f; a11 *= 0.1f; a12 *= 0.1f; a22 *= 0.1f;
    #pragma unroll
    for (int sweep = 0; sweep < 6; ++sweep) {
        jrot(a00, a11, a01, a02, a12);
        jrot(a00, a22, a02, a01, a12);
        jrot(a11, a22, a12, a01, a02);
    }
    float e0 = a00, e1 = a11, e2 = a22, tmp;
    if (e0 > e1) { tmp = e0; e0 = e1; e1 = tmp; }
    if (e1 > e2) { tmp = e1; e1 = e2; e2 = tmp; }
    if (e0 > e1) { tmp = e0; e0 = e1; e1 = tmp; }
    float tt[4];
    #pragma unroll
    for (int i = 0; i < 4; ++i) {
        float v = be1[i];
        v = fmaf(e0, We1[i], v);
        v = fmaf(e1, We1[4 + i], v);
        v = fmaf(e2, We1[8 + i], v);
        tt[i] = fmaxf(v, 0.f);
    }
    #pragma unroll
    for (int i = 0; i < 4; ++i) {
        float v = be2[i];
        v = fmaf(tt[0], We2[i], v);
        v = fmaf(tt[1], We2[4 + i], v);
        v = fmaf(tt[2], We2[8 + i], v);
        v = fmaf(tt[3], We2[12 + i], v);
        ef[t * 4 + i] = v;
    }
}

// ---------------- K3: ball query (via merged 10-NN) + SA MLP + maxpool ----------------
__global__ __launch_bounds__(256) void k_sa(const float4* __restrict__ cand4,
                                            const float* __restrict__ data,
                                            const float* __restrict__ f0,
                                            const uint32_t* __restrict__ mrg,
                                            const float* __restrict__ Wsa,
                                            const float* __restrict__ bsa,
                                            float* __restrict__ fsub) {
    __shared__ float2 sW[67 * 64];
    __shared__ int sIdx[4][NS];
    for (int i = threadIdx.x; i < 67 * 64; i += 256) {
        int k = i >> 6, c = i & 63;
        sW[i] = make_float2(Wsa[k * 128 + c], Wsa[k * 128 + 64 + c]);
    }
    __syncthreads();
    int wv = threadIdx.x >> 6, lane = threadIdx.x & 63;
    int gm = blockIdx.x * 4 + wv;
    if (gm >= BB * MM) return;
    int b = gm / MM, m = gm - b * MM;
    const float4* cb4 = cand4 + b * NN;
    const float* db = data + b * NN * 3;
    float4 cen = cb4[3 * m];
    float cx = cen.x, cy = cen.y, cz = cen.z, sa = cen.w;

    // fast ball query: exact-d2 filter of the merged 10-NN
    int cnt;
    bool fallback;
    {
        float d2l = 1e30f;
        int idxl = 0;
        if (lane < 10) {
            uint32_t key = mrg[lane * (BB * NN) + b * NN + 3 * m];
            idxl = (int)(key & 0xFFFu);
            float4 c = cb4[idxl];
            float dot = fmaf(cz, c.z, fmaf(cy, c.y, cx * c.x));
            d2l = (sa + c.w) - 2.f * dot;
        }
        bool valid = (lane < 10) && (d2l < RAD2);
        unsigned long long mask = __ballot(valid);
        if (valid) sIdx[wv][__popcll(mask & ((1ull << lane) - 1ull))] = idxl;
        cnt = __popcll(mask);
        fallback = rl(d2l, 9) < RAD2 * 1.0005f;   // ball might exceed top-10
    }
    if (fallback) {
        cnt = 0;
        for (int base = 0; base < NN; base += 64) {
            int n = base + lane;
            float4 c = cb4[n];
            float dot = fmaf(cz, c.z, fmaf(cy, c.y, cx * c.x));
            float d2 = (sa + c.w) - 2.f * dot;
            bool valid = d2 < RAD2;
            unsigned long long mask = __ballot(valid);
            if (valid) {
                int pos = cnt + __popcll(mask & ((1ull << lane) - 1ull));
                if (pos < NS) sIdx[wv][pos] = n;
            }
            cnt += __popcll(mask);
            if (cnt >= NS) break;
        }
    }
    int scnt = cnt < NS ? cnt : NS;

    float cl = lane == 0 ? cx : (lane == 1 ? cy : cz);
    float hb0 = bsa[lane], hb1 = bsa[64 + lane];
    float m0 = 0.f, m1 = 0.f;       // relu outputs >= 0

    for (int s0 = 0; s0 < scnt; s0 += 4) {
        float fr[4], fr2[4];
        #pragma unroll
        for (int u = 0; u < 4; ++u) {
            int s = s0 + u;
            if (s >= scnt) s = 0;          // pad with sample 0 (real, max-safe)
            int nj = sIdx[wv][s];
            int fb = (b * NN + nj) * 64;
            float v;
            if (lane >= 3) v = f0[fb + lane - 3];
            else           v = (db[nj * 3 + lane] - cl) * 10.0f;   // dp = diff/0.1
            fr[u] = v;
            fr2[u] = (lane < 3) ? f0[fb + 61 + lane] : 0.f;
        }
        float h0[4], h1[4];
        #pragma unroll
        for (int u = 0; u < 4; ++u) { h0[u] = hb0; h1[u] = hb1; }
        for (int k = 0; k < 64; ++k) {
            float2 w = sW[k * 64 + lane];
            #pragma unroll
            for (int u = 0; u < 4; ++u) {
                float fv = rl(fr[u], k);
                h0[u] = fmaf(fv, w.x, h0[u]);
                h1[u] = fmaf(fv, w.y, h1[u]);
            }
        }
        #pragma unroll
        for (int k = 64; k < 67; ++k) {
            float2 w = sW[k * 64 + lane];
            #pragma unroll
            for (int u = 0; u < 4; ++u) {
                float fv = rl(fr2[u], k - 64);
                h0[u] = fmaf(fv, w.x, h0[u]);
                h1[u] = fmaf(fv, w.y, h1[u]);
            }
        }
        #pragma unroll
        for (int u = 0; u < 4; ++u) {
            m0 = fmaxf(m0, fmaxf(h0[u], 0.f));
            m1 = fmaxf(m1, fmaxf(h1[u], 0.f));
        }
    }
    fsub[gm * 128 + lane] = m0;
    fsub[gm * 128 + 64 + lane] = m1;
}

// ---------------- K4: 3-NN among centers + inverse-distance interp ----------------
__global__ __launch_bounds__(512) void k_interp(const float4* __restrict__ cand4,
                                                const float* __restrict__ fsub,
                                                float* __restrict__ itp) {
    __shared__ float4 sC[MM];
    __shared__ float sMD[8][64][3];
    __shared__ int   sMI[8][64][3];
    __shared__ float sWts[64][3];
    __shared__ int   sNbr[64][3];
    int t = threadIdx.x, wv = t >> 6, lane = t & 63;
    int blk = blockIdx.x;
    int b = blk >> 6;
    int pbase = (blk & 63) * 64;
    const float4* cb4 = cand4 + b * NN;
    for (int m = t; m < MM; m += 512) sC[m] = cb4[3 * m];
    __syncthreads();
    int p = pbase + lane;
    float4 pm = cb4[p];
    float px = pm.x, py = pm.y, pz = pm.z, pa = pm.w;
    float d0 = 1e30f, d1 = 1e30f, d2v = 1e30f;
    int n0 = 0, n1 = 0, n2 = 0;
    int ms = wv * 171, me = ms + 171 < MM ? ms + 171 : MM;
    for (int m = ms; m < me; ++m) {
        float4 c = sC[m];
        float dd = (pa + c.w) - 2.f * (px * c.x + py * c.y + pz * c.z);
        if (dd < d2v) {
            if (dd < d1) {
                d2v = d1; n2 = n1;
                if (dd < d0) { d1 = d0; n1 = n0; d0 = dd; n0 = m; }
                else         { d1 = dd; n1 = m; }
            } else { d2v = dd; n2 = m; }
        }
    }
    sMD[wv][lane][0] = d0; sMD[wv][lane][1] = d1; sMD[wv][lane][2] = d2v;
    sMI[wv][lane][0] = n0; sMI[wv][lane][1] = n1; sMI[wv][lane][2] = n2;
    __syncthreads();
    if (wv == 0) {
        d0 = sMD[0][lane][0]; d1 = sMD[0][lane][1]; d2v = sMD[0][lane][2];
        n0 = sMI[0][lane][0]; n1 = sMI[0][lane][1]; n2 = sMI[0][lane][2];
        for (int w = 1; w < 8; ++w) {
            #pragma unroll
            for (int r = 0; r < 3; ++r) {
                float dd = sMD[w][lane][r];
                int mm = sMI[w][lane][r];
                if (dd < d2v) {
                    if (dd < d1) {
                        d2v = d1; n2 = n1;
                        if (dd < d0) { d1 = d0; n1 = n0; d0 = dd; n0 = mm; }
                        else         { d1 = dd; n1 = mm; }
                    } else { d2v = dd; n2 = mm; }
                }
            }
        }
        float w0 = 1.f / (d0 + 1e-8f), w1 = 1.f / (d1 + 1e-8f), w2 = 1.f / (d2v + 1e-8f);
        float ws = w0 + w1 + w2;
        sWts[lane][0] = w0 / ws; sWts[lane][1] = w1 / ws; sWts[lane][2] = w2 / ws;
        sNbr[lane][0] = n0; sNbr[lane][1] = n1; sNbr[lane][2] = n2;
    }
    __syncthreads();
    for (int i = wv * 8; i < wv * 8 + 8; ++i) {
        float a0 = sWts[i][0], a1 = sWts[i][1], a2 = sWts[i][2];
        const float* r0 = fsub + (b * MM + sNbr[i][0]) * 128;
        const float* r1 = fsub + (b * MM + sNbr[i][1]) * 128;
        const float* r2 = fsub + (b * MM + sNbr[i][2]) * 128;
        float v0 = fmaf(a2, r2[lane], fmaf(a1, r1[lane], a0 * r0[lane]));
        float v1 = fmaf(a2, r2[64 + lane], fmaf(a1, r1[64 + lane], a0 * r0[64 + lane]));
        int row = b * NN + pbase + i;
        itp[row * 128 + lane] = v0;
        itp[row * 128 + 64 + lane] = v1;
    }
}

// ---------------- K5: f = relu([interp, f0] @ W_fp + b_fp) ----------------
__global__ __launch_bounds__(256) void k_fp(const float* __restrict__ itp,
                                            const float* __restrict__ f0,
                                            const float* __restrict__ W,
                                            const float* __restrict__ bias,
                                            float* __restrict__ outf) {
    __shared__ float sW[192 * 64];
    for (int i = threadIdx.x; i < 192 * 64; i += 256) sW[i] = W[i];
    __syncthreads();
    int lane = threadIdx.x & 63;
    int wv = threadIdx.x >> 6;
    float bb = bias[lane];
    int rowbase = blockIdx.x * 64 + wv * 16;
    for (int it = 0; it < 4; ++it) {
        int r = rowbase + it * 4;
        float fa[4], fbv[4], fc[4], acc[4];
        #pragma unroll
        for (int u = 0; u < 4; ++u) {
            fa[u]  = itp[(r + u) * 128 + lane];
            fbv[u] = itp[(r + u) * 128 + 64 + lane];
            fc[u]  = f0[(r + u) * 64 + lane];
            acc[u] = bb;
        }
        #pragma unroll
        for (int k = 0; k < 192; ++k) {
            float w = sW[k * 64 + lane];
            #pragma unroll
            for (int u = 0; u < 4; ++u) {
                float fv = k < 64 ? rl(fa[u], k)
                         : (k < 128 ? rl(fbv[u], k - 64) : rl(fc[u], k - 128));
                acc[u] = fmaf(fv, w, acc[u]);
            }
        }
        #pragma unroll
        for (int u = 0; u < 4; ++u)
            outf[(r + u) * 64 + lane] = fmaxf(acc[u], 0.f);
    }
}

// ---------------- K6: zc = [f, ef] @ W_fin + b_fin ----------------
__global__ __launch_bounds__(256) void k_fin(const float* __restrict__ fb,
                                             const float* __restrict__ efb,
                                             const float* __restrict__ W,
                                             const float* __restrict__ bias,
                                             float* __restrict__ zc) {
    __shared__ float sW[68 * 64];
    for (int i = threadIdx.x; i < 68 * 64; i += 256) sW[i] = W[i];
    __syncthreads();
    int lane = threadIdx.x & 63;
    int wv = threadIdx.x >> 6;
    float bb = bias[lane];
    int rowbase = blockIdx.x * 64 + wv * 16;
    for (int it = 0; it < 4; ++it) {
        int r = rowbase + it * 4;
        float fa[4], fe[4], acc[4];
        #pragma unroll
        for (int u = 0; u < 4; ++u) {
            fa[u] = fb[(r + u) * 64 + lane];
            fe[u] = (lane < 4) ? efb[(r + u) * 4 + lane] : 0.f;
            acc[u] = bb;
        }
        #pragma unroll
        for (int k = 0; k < 68; ++k) {
            float w = sW[k * 64 + lane];
            #pragma unroll
            for (int u = 0; u < 4; ++u) {
                float fv = k < 64 ? rl(fa[u], k) : rl(fe[u], k - 64);
                acc[u] = fmaf(fv, w, acc[u]);
            }
        }
        #pragma unroll
        for (int u = 0; u < 4; ++u)
            zc[(r + u) * 64 + lane] = acc[u];
    }
}

// ---------------- K7: batchnorm stats, two-stage ----------------
__global__ __launch_bounds__(256) void k_stats1(const float* __restrict__ zc,
                                                float* __restrict__ pp) {
    int t = threadIdx.x;
    int c = t & 63, r4 = t >> 6;
    float s = 0.f, sq = 0.f;
    int base = blockIdx.x * 512;
    for (int i = 0; i < 128; ++i) {
        float v = zc[(base + i * 4 + r4) * 64 + c];
        s += v;
        sq = fmaf(v, v, sq);
    }
    __shared__ float ls[256], lq[256];
    ls[t] = s; lq[t] = sq;
    __syncthreads();
    if (t < 64) {
        float st = ls[t] + ls[t + 64] + ls[t + 128] + ls[t + 192];
        float qt = lq[t] + lq[t + 64] + lq[t + 128] + lq[t + 192];
        pp[blockIdx.x * 128 + t] = st;
        pp[blockIdx.x * 128 + 64 + t] = qt;
    }
}

__global__ __launch_bounds__(64) void k_stats2(const float* __restrict__ pp,
                                               const float* __restrict__ gamma,
                                               const float* __restrict__ beta,
                                               float* __restrict__ ss) {
    int c = threadIdx.x;
    float s = 0.f, sq = 0.f;
    for (int k = 0; k < 64; ++k) {
        s += pp[k * 128 + c];
        sq += pp[k * 128 + 64 + c];
    }
    const float inv = 1.f / (float)(BB * NN);
    float mu = s * inv;
    float var = sq * inv - mu * mu;
    float sc = gamma[c] / sqrtf(var + 1e-5f);
    ss[c] = sc;
    ss[64 + c] = beta[c] - mu * sc;
}

// ---------------- K8: normalize + relu + transpose ----------------
__global__ __launch_bounds__(256) void k_norm_t(const float* __restrict__ zc,
                                                const float* __restrict__ ss,
                                                float* __restrict__ out) {
    __shared__ float sT[64][65];
    int blk = blockIdx.x;
    int b = blk >> 6;
    int nbase = (blk & 63) * 64;
    int c = threadIdx.x & 63;
    int r4 = threadIdx.x >> 6;
    float sc = ss[c], sh = ss[64 + c];
    #pragma unroll
    for (int i = 0; i < 16; ++i) {
        int nr = i * 4 + r4;
        float v = zc[(b * NN + nbase + nr) * 64 + c];
        sT[nr][c] = fmaxf(fmaf(v, sc, sh), 0.f);
    }
    __syncthreads();
    int nn = threadIdx.x & 63;
    #pragma unroll
    for (int i = 0; i < 16; ++i) {
        int cc = i * 4 + r4;
        out[BB * NN * 3 + (b * 64 + cc) * NN + nbase + nn] = sT[nn][cc];
    }
}

extern "C" void kernel_launch(void* const* d_in, const int* in_sizes, int n_in,
                              void* d_out, int out_size, void* d_ws, size_t ws_size,
                              hipStream_t stream) {
    const float* data = (const float*)d_in[0];
    const float* Wst  = (const float*)d_in[2];
    const float* bst  = (const float*)d_in[3];
    const float* Wsa  = (const float*)d_in[4];
    const float* bsa  = (const float*)d_in[5];
    const float* Wfp  = (const float*)d_in[6];
    const float* bfp  = (const float*)d_in[7];
    const float* We1  = (const float*)d_in[8];
    const float* be1  = (const float*)d_in[9];
    const float* We2  = (const float*)d_in[10];
    const float* be2  = (const float*)d_in[11];
    const float* Wfin = (const float*)d_in[12];
    const float* bfin = (const float*)d_in[13];
    const float* gamma = (const float*)d_in[14];
    const float* beta  = (const float*)d_in[15];
    float* out = (float*)d_out;

    // layout (floats): buffers consumed late come last so scratch can alias them
    float* f0   = (float*)d_ws;            // 2,097,152
    float* fsub = f0 + 2097152;            // 1,398,784
    float* efb  = fsub + 1398784;          //   131,072
    float* zc   = efb + 131072;            // 2,097,152
    float* ss   = zc + 2097152;            //       128
    float* pp   = ss + 128;                //     8,192
    float4* cand4 = (float4*)(pp + 8192);  //   131,072 floats, 16B-aligned
    uint32_t* mrgb = (uint32_t*)((float*)cand4 + 131072);   // 1,310,720 u32 region
    float* itp  = (float*)mrgb + 1310720;  // 4,194,304
    float* fb   = itp + 4194304;           // 2,097,152
    // sort scratch (cand4s 131,072 + perm 32,768 + gbox 4,096 words) aliases itp:
    // fully consumed by k_knn before k_interp writes itp.
    float4*   cand4s = (float4*)itp;
    uint32_t* perm   = (uint32_t*)(itp + 131072);
    float4*   gbox   = (float4*)(itp + 131072 + 32768);

    // stem grid: 8192 stem blocks + 128 prep blocks (block-level split)
    k_stem<<<(BB * NN * 64) / 256 + (BB * NN) / 256, 256, 0, stream>>>(
        data, Wst, bst, f0, out, cand4);
    k_sort<<<BB, 256, 0, stream>>>(cand4, cand4s, perm, gbox);
    k_knn<<<BB * NGRP, 512, 0, stream>>>(cand4s, perm, gbox, mrgb);
    k_knn_eig<<<(BB * NN) / 256, 256, 0, stream>>>(cand4, mrgb, We1, be1, We2, be2, efb);
    k_sa<<<(BB * MM + 3) / 4, 256, 0, stream>>>(cand4, data, f0, mrgb, Wsa, bsa, fsub);
    k_interp<<<BB * 64, 512, 0, stream>>>(cand4, fsub, itp);
    k_fp<<<512, 256, 0, stream>>>(itp, f0, Wfp, bfp, fb);
    k_fin<<<512, 256, 0, stream>>>(fb, efb, Wfin, bfin, zc);
    k_stats1<<<64, 256, 0, stream>>>(zc, pp);
    k_stats2<<<1, 64, 0, stream>>>(pp, gamma, beta, ss);
    k_norm_t<<<512, 256, 0, stream>>>(zc, ss, out);
}

// Round 6
// 336.154 us; speedup vs baseline: 1.0195x; 1.0195x over previous
//
#include <hip/hip_runtime.h>
#include <stdint.h>

#define BB 8
#define NN 4096
#define MM 1366   // len(arange(0,4096,3))
#define NS 32
#define RAD2 0.01f
#define NGRP 64          // groups of 64 sorted points per batch
#define KW 4             // waves (slots) per k_knn block

__device__ __forceinline__ float rl(float v, int l) {
    return __int_as_float(__builtin_amdgcn_readlane(__float_as_int(v), l));
}
__device__ __forceinline__ uint32_t um(uint32_t a, uint32_t b) { return a < b ? a : b; }
__device__ __forceinline__ uint32_t ux(uint32_t a, uint32_t b) { return a > b ? a : b; }
__device__ __forceinline__ uint32_t um3(uint32_t a, uint32_t b, uint32_t c) { return um(um(a, b), c); }

// merge sorted pair (s0<=s1) into sorted-10 kk
__device__ __forceinline__ void mrg2(uint32_t* kk, uint32_t s0, uint32_t s1) {
    uint32_t n0 = um(kk[0], s0);
    uint32_t n1 = um3(kk[1], ux(kk[0], s0), s1);
    uint32_t n2 = um3(kk[2], ux(kk[1], s0), ux(kk[0], s1));
    uint32_t n3 = um3(kk[3], ux(kk[2], s0), ux(kk[1], s1));
    uint32_t n4 = um3(kk[4], ux(kk[3], s0), ux(kk[2], s1));
    uint32_t n5 = um3(kk[5], ux(kk[4], s0), ux(kk[3], s1));
    uint32_t n6 = um3(kk[6], ux(kk[5], s0), ux(kk[4], s1));
    uint32_t n7 = um3(kk[7], ux(kk[6], s0), ux(kk[5], s1));
    uint32_t n8 = um3(kk[8], ux(kk[7], s0), ux(kk[6], s1));
    uint32_t n9 = um3(kk[9], ux(kk[8], s0), ux(kk[7], s1));
    kk[0]=n0; kk[1]=n1; kk[2]=n2; kk[3]=n3; kk[4]=n4;
    kk[5]=n5; kk[6]=n6; kk[7]=n7; kk[8]=n8; kk[9]=n9;
}

// merge sorted quad (s0<=s1<=s2<=s3) into sorted-10 kk
__device__ __forceinline__ void mrg4(uint32_t* kk, uint32_t s0, uint32_t s1,
                                     uint32_t s2, uint32_t s3) {
    uint32_t n0 = um(kk[0], s0);
    uint32_t n1 = um3(kk[1], ux(kk[0], s0), s1);
    uint32_t n2 = um(um3(kk[2], ux(kk[1], s0), ux(kk[0], s1)), s2);
    uint32_t n3 = um3(um3(kk[3], ux(kk[2], s0), ux(kk[1], s1)), ux(kk[0], s2), s3);
    uint32_t n4 = um3(um3(kk[4], ux(kk[3], s0), ux(kk[2], s1)), ux(kk[1], s2), ux(kk[0], s3));
    uint32_t n5 = um3(um3(kk[5], ux(kk[4], s0), ux(kk[3], s1)), ux(kk[2], s2), ux(kk[1], s3));
    uint32_t n6 = um3(um3(kk[6], ux(kk[5], s0), ux(kk[4], s1)), ux(kk[3], s2), ux(kk[2], s3));
    uint32_t n7 = um3(um3(kk[7], ux(kk[6], s0), ux(kk[5], s1)), ux(kk[4], s2), ux(kk[3], s3));
    uint32_t n8 = um3(um3(kk[8], ux(kk[7], s0), ux(kk[6], s1)), ux(kk[5], s2), ux(kk[4], s3));
    uint32_t n9 = um3(um3(kk[9], ux(kk[8], s0), ux(kk[7], s1)), ux(kk[6], s2), ux(kk[5], s3));
    kk[0]=n0; kk[1]=n1; kk[2]=n2; kk[3]=n3; kk[4]=n4;
    kk[5]=n5; kk[6]=n6; kk[7]=n7; kk[8]=n8; kk[9]=n9;
}

// sort 4 keys ascending: 5-CE network
__device__ __forceinline__ void srt4(uint32_t& a, uint32_t& b, uint32_t& c, uint32_t& d) {
    uint32_t t0 = um(a, b), t1 = ux(a, b), t2 = um(c, d), t3 = ux(c, d);
    uint32_t s0 = um(t0, t2), m0 = ux(t0, t2), m1 = um(t1, t3), s3 = ux(t1, t3);
    a = s0; b = um(m0, m1); c = ux(m0, m1); d = s3;
}

// spread 4 bits to every 3rd bit position (0,3,6,9)
__device__ __forceinline__ uint32_t spr3(uint32_t v) {
    v = (v | (v << 4)) & 0xC3u;
    v = (v | (v << 2)) & 0x249u;
    return v;
}

// ---------------- K1: stem (+ prep absorbed as extra blocks) ----------------
__global__ __launch_bounds__(256) void k_stem(const float* __restrict__ data,
                                              const float* __restrict__ Ws,
                                              const float* __restrict__ bs,
                                              float* __restrict__ f0,
                                              float* __restrict__ out,
                                              float4* __restrict__ cand4) {
    int blk = blockIdx.x;
    if (blk >= (BB * NN * 64) / 256) {
        // prep blocks: copy data -> out, build cand4 = (x,y,z,|p|^2)
        int t = (blk - (BB * NN * 64) / 256) * 256 + threadIdx.x;   // BB*NN
        float x = data[t * 3], y = data[t * 3 + 1], z = data[t * 3 + 2];
        out[t * 3] = x; out[t * 3 + 1] = y; out[t * 3 + 2] = z;
        cand4[t] = make_float4(x, y, z, x * x + y * y + z * z);
        return;
    }
    int t = blk * 256 + threadIdx.x;
    int c = t & 63;
    int r = t >> 6;
    const float* d = data + r * 3;
    float acc = bs[c];
    acc = fmaf(d[0], Ws[c], acc);
    acc = fmaf(d[1], Ws[64 + c], acc);
    acc = fmaf(d[2], Ws[128 + c], acc);
    f0[t] = fmaxf(acc, 0.f);
}

// ---------------- K1b: Morton counting-sort of each batch + per-group bboxes ----------------
__global__ __launch_bounds__(256) void k_sort(const float4* __restrict__ cand4,
                                              float4* __restrict__ cand4s,
                                              uint32_t* __restrict__ perm,
                                              float4* __restrict__ gbox) {
    __shared__ uint32_t cnt[4096];   // 16^3 Morton cells
    __shared__ uint32_t part[256];
    int b = blockIdx.x, t = threadIdx.x;
    const float4* cb = cand4 + b * NN;
    for (int i = t; i < 4096; i += 256) cnt[i] = 0;
    __syncthreads();
    uint32_t cid[16];
    #pragma unroll
    for (int u = 0; u < 16; ++u) {
        float4 c = cb[u * 256 + t];
        int ix = (int)floorf((c.x + 4.f) * 2.f);
        int iy = (int)floorf((c.y + 4.f) * 2.f);
        int iz = (int)floorf((c.z + 4.f) * 2.f);
        ix = ix < 0 ? 0 : (ix > 15 ? 15 : ix);
        iy = iy < 0 ? 0 : (iy > 15 ? 15 : iy);
        iz = iz < 0 ? 0 : (iz > 15 ? 15 : iz);
        uint32_t m = spr3((uint32_t)ix) | (spr3((uint32_t)iy) << 1) | (spr3((uint32_t)iz) << 2);
        cid[u] = m;
        atomicAdd(&cnt[m], 1u);
    }
    __syncthreads();
    // prefix sum over 4096 bins: 16 serial per thread + block scan of 256
    uint32_t c16[16];
    uint32_t s = 0;
    #pragma unroll
    for (int u = 0; u < 16; ++u) { c16[u] = cnt[t * 16 + u]; s += c16[u]; }
    part[t] = s;
    __syncthreads();
    for (int off = 1; off < 256; off <<= 1) {
        uint32_t v = (t >= off) ? part[t - off] : 0u;
        __syncthreads();
        part[t] += v;
        __syncthreads();
    }
    uint32_t run = part[t] - s;   // exclusive prefix of this thread's 16 bins
    #pragma unroll
    for (int u = 0; u < 16; ++u) { cnt[t * 16 + u] = run; run += c16[u]; }
    __syncthreads();
    // scatter (order within cell irrelevant: selection later is an exact total order)
    #pragma unroll
    for (int u = 0; u < 16; ++u) {
        int p = u * 256 + t;
        uint32_t pos = atomicAdd(&cnt[cid[u]], 1u);
        cand4s[b * NN + pos] = cb[p];
        perm[b * NN + pos] = (uint32_t)p;   // 12-bit local original index
    }
    __syncthreads();   // drains vmcnt: our global writes are visible to our reads below
    // per-group (64 sorted points) bounding boxes
    if (t < NGRP) {
        float4 mn = make_float4(1e30f, 1e30f, 1e30f, 0.f);
        float4 mx = make_float4(-1e30f, -1e30f, -1e30f, 0.f);
        for (int j = 0; j < 64; ++j) {
            float4 c = cand4s[b * NN + t * 64 + j];
            mn.x = fminf(mn.x, c.x); mn.y = fminf(mn.y, c.y); mn.z = fminf(mn.z, c.z);
            mx.x = fmaxf(mx.x, c.x); mx.y = fmaxf(mx.y, c.y); mx.z = fmaxf(mx.z, c.z);
        }
        gbox[(b * NGRP + t) * 2]     = mn;
        gbox[(b * NGRP + t) * 2 + 1] = mx;
    }
}

// ---------------- K2: exact top-10 NN, a-priori home bound, no cross-wave deps ----------------
// Block = query group g (4 waves). Every wave scans the home group (64 sorted
// neighbors) -> a-priori upper bound ub_key on the true 10th key (true10 <= home10).
// Waves 1..3 then RESET their lists (g's keys live only in wave0's list -> no dups)
// and each wave scans a stride-4 slice of the other 63 groups, gated by a per-lane
// point-box lower bound vs min(kk[9], ub) and the per-packet ballot skip vs the same
// threshold. Exact: any final top-10 member has key < true10key <= home10key < ub_key,
// so its (unique) owning wave neither box-skips its group nor ballot-skips its packet.
// One barrier, one 3-list merge, no extension rounds, no shfl-argmin chains.
__global__ __launch_bounds__(256) void k_knn(const float4* __restrict__ cand4s,
                                             const uint32_t* __restrict__ perm,
                                             const float4* __restrict__ gbox,
                                             uint32_t* __restrict__ mrg) {
    __shared__ float4 sBox[2 * NGRP];
    __shared__ uint32_t sKK[KW - 1][64][10];
    int t = threadIdx.x, w = t >> 6, lane = t & 63;
    int gw = blockIdx.x;           // global group id 0..511
    int b = gw >> 6;
    int g = gw & (NGRP - 1);
    for (int i = t; i < 2 * NGRP; i += 256) sBox[i] = gbox[b * 2 * NGRP + i];
    __syncthreads();
    const float4* cs = cand4s + b * NN;
    const uint32_t* ps = perm + b * NN;
    float4 me = cs[g * 64 + lane];
    uint32_t mo = ps[g * 64 + lane];
    float px = me.x, py = me.y, pz = me.z, pa = me.w;
    uint32_t kk[10];
    #pragma unroll
    for (int r = 0; r < 10; ++r) kk[r] = 0xFFFFFF00u + r;   // ascending sentinels

    auto scan_packets = [&](int jg, uint32_t thrC) {
        const float4* cp = cs + jg * 64;
        const uint4* pq = (const uint4*)(ps + jg * 64);
        uint32_t thr = um(kk[9], thrC);
        for (int j = 0; j < 16; ++j) {
            float4 ca  = cp[j * 4];
            float4 cbv = cp[j * 4 + 1];
            float4 cc  = cp[j * 4 + 2];
            float4 cd  = cp[j * 4 + 3];
            uint4 pm = pq[j];
            float da  = fmaxf(fmaf(-2.f, fmaf(pz, ca.z,  fmaf(py, ca.y,  px * ca.x)),  pa + ca.w),  0.f);
            float db_ = fmaxf(fmaf(-2.f, fmaf(pz, cbv.z, fmaf(py, cbv.y, px * cbv.x)), pa + cbv.w), 0.f);
            float dc  = fmaxf(fmaf(-2.f, fmaf(pz, cc.z,  fmaf(py, cc.y,  px * cc.x)),  pa + cc.w),  0.f);
            float dd  = fmaxf(fmaf(-2.f, fmaf(pz, cd.z,  fmaf(py, cd.y,  px * cd.x)),  pa + cd.w),  0.f);
            uint32_t ka = (__float_as_uint(da)  & 0xFFFFF000u) | pm.x;
            uint32_t kb = (__float_as_uint(db_) & 0xFFFFF000u) | pm.y;
            uint32_t kc = (__float_as_uint(dc)  & 0xFFFFF000u) | pm.z;
            uint32_t kd = (__float_as_uint(dd)  & 0xFFFFF000u) | pm.w;
            uint32_t mn4 = um(um(ka, kb), um(kc, kd));
            if (__ballot(mn4 < thr)) {       // wave-uniform: skip if nobody can improve
                srt4(ka, kb, kc, kd);
                mrg4(kk, ka, kb, kc, kd);
                thr = um(kk[9], thrC);
            }
        }
    };

    scan_packets(g, 0xFFFFFFFFu);            // home scan (all waves, redundant)

    // a-priori bound key: wave-max of (home 10th key, +1 ulp at 20-bit granularity)
    uint32_t ub_key;
    {
        uint32_t kb9 = (kk[9] & 0xFFFFF000u) + 0x1000u;   // 64 real cands -> no sentinel
        #pragma unroll
        for (int off = 1; off < 64; off <<= 1) {
            uint32_t o = (uint32_t)__shfl_xor((int)kb9, off);
            kb9 = ux(kb9, o);
        }
        ub_key = kb9;
    }

    if (w > 0) {                             // reset: g's keys only in wave0's list
        #pragma unroll
        for (int r = 0; r < 10; ++r) kk[r] = 0xFFFFFF00u + r;
    }

    for (int jg = w; jg < NGRP; jg += KW) {
        if (jg == g) continue;
        float4 bmn = sBox[jg * 2], bmx = sBox[jg * 2 + 1];
        float dx = fmaxf(fmaxf(bmn.x - px, px - bmx.x), 0.f);
        float dy = fmaxf(fmaxf(bmn.y - py, py - bmx.y), 0.f);
        float dz = fmaxf(fmaxf(bmn.z - pz, pz - bmx.z), 0.f);
        float lb = fmaf(dx, dx, fmaf(dy, dy, dz * dz));
        uint32_t mt = um(kk[9], ub_key);
        float tf = __uint_as_float((mt & 0xFFFFF000u) + 0x1000u) * 1.0005f;
        if (__ballot(lb < tf))               // any lane could improve -> scan group
            scan_packets(jg, ub_key);
    }

    if (w > 0) {
        #pragma unroll
        for (int r = 0; r < 10; ++r) sKK[w - 1][lane][r] = kk[r];
    }
    __syncthreads();
    if (w == 0) {
        for (int ww = 0; ww < KW - 1; ++ww) {
            uint32_t s[10];
            #pragma unroll
            for (int r = 0; r < 10; ++r) s[r] = sKK[ww][lane][r];
            mrg4(kk, s[0], s[1], s[2], s[3]);
            mrg4(kk, s[4], s[5], s[6], s[7]);
            mrg2(kk, s[8], s[9]);
        }
        int gp = b * NN + (int)mo;
        #pragma unroll
        for (int r = 0; r < 10; ++r) mrg[r * (BB * NN) + gp] = kk[r];
    }
}

// ---------------- K2b: cov, Jacobi eig, eig-MLP from merged 10-NN ----------------
__device__ __forceinline__ void jrot(float& app, float& aqq, float& apq,
                                     float& arp, float& arq) {
    float ap = apq;
    if (fabsf(ap) > 1e-32f) {
        float th = (aqq - app) / (2.f * ap);
        float t = 1.f / (fabsf(th) + sqrtf(th * th + 1.f));
        t = th < 0.f ? -t : t;
        float c = 1.f / sqrtf(t * t + 1.f);
        float s = t * c;
        app = app - t * ap;
        aqq = aqq + t * ap;
        apq = 0.f;
        float rp = arp, rq = arq;
        arp = c * rp - s * rq;
        arq = s * rp + c * rq;
    }
}

__global__ __launch_bounds__(256) void k_knn_eig(const float4* __restrict__ cand4,
                                                 const uint32_t* __restrict__ mrg,
                                                 const float* __restrict__ We1,
                                                 const float* __restrict__ be1,
                                                 const float* __restrict__ We2,
                                                 const float* __restrict__ be2,
                                                 float* __restrict__ ef) {
    int t = blockIdx.x * 256 + threadIdx.x;   // B*N
    int b = t >> 12;
    const float4* cb = cand4 + b * NN;
    uint32_t kk[10];
    #pragma unroll
    for (int r = 0; r < 10; ++r) kk[r] = mrg[r * (BB * NN) + t];
    float xs[10], ys[10], zs[10];
    float mx = 0.f, my = 0.f, mz = 0.f;
    #pragma unroll
    for (int r = 0; r < 10; ++r) {
        int n = (int)(kk[r] & 0xFFFu);
        float4 cr = cb[n];
        xs[r] = cr.x; ys[r] = cr.y; zs[r] = cr.z;
        mx += xs[r]; my += ys[r]; mz += zs[r];
    }
    mx *= 0.1f; my *= 0.1f; mz *= 0.1f;
    float a00 = 0, a01 = 0, a02 = 0, a11 = 0, a12 = 0, a22 = 0;
    #pragma unroll
    for (int r = 0; r < 10; ++r) {
        float x = xs[r] - mx, y = ys[r] - my, z = zs[r] - mz;
        a00 = fmaf(x, x, a00); a01 = fmaf(x, y, a01); a02 = fmaf(x, z, a02);
        a11 = fmaf(y, y, a11); a12 = fmaf(y, z, a12); a22 = fmaf(z, z, a22);
    }
    a00 *= 0.1f; a01 *= 0.1f; a02 *= 0.1f; a11 *= 0.1f; a12 *= 0.1f; a22 *= 0.1f;
    #pragma unroll
    for (int sweep = 0; sweep < 6; ++sweep) {
        jrot(a00, a11, a01, a02, a12);
        jrot(a00, a22, a02, a01, a12);
        jrot(a11, a22, a12, a01, a02);
    }
    float e0 = a00, e1 = a11, e2 = a22, tmp;
    if (e0 > e1) { tmp = e0; e0 = e1; e1 = tmp; }
    if (e1 > e2) { tmp = e1; e1 = e2; e2 = tmp; }
    if (e0 > e1) { tmp = e0; e0 = e1; e1 = tmp; }
    float tt[4];
    #pragma unroll
    for (int i = 0; i < 4; ++i) {
        float v = be1[i];
        v = fmaf(e0, We1[i], v);
        v = fmaf(e1, We1[4 + i], v);
        v = fmaf(e2, We1[8 + i], v);
        tt[i] = fmaxf(v, 0.f);
    }
    #pragma unroll
    for (int i = 0; i < 4; ++i) {
        float v = be2[i];
        v = fmaf(tt[0], We2[i], v);
        v = fmaf(tt[1], We2[4 + i], v);
        v = fmaf(tt[2], We2[8 + i], v);
        v = fmaf(tt[3], We2[12 + i], v);
        ef[t * 4 + i] = v;
    }
}

// ---------------- K3: ball query (via merged 10-NN) + SA MLP + maxpool ----------------
__global__ __launch_bounds__(256) void k_sa(const float4* __restrict__ cand4,
                                            const float* __restrict__ data,
                                            const float* __restrict__ f0,
                                            const uint32_t* __restrict__ mrg,
                                            const float* __restrict__ Wsa,
                                            const float* __restrict__ bsa,
                                            float* __restrict__ fsub) {
    __shared__ float2 sW[67 * 64];
    __shared__ int sIdx[4][NS];
    for (int i = threadIdx.x; i < 67 * 64; i += 256) {
        int k = i >> 6, c = i & 63;
        sW[i] = make_float2(Wsa[k * 128 + c], Wsa[k * 128 + 64 + c]);
    }
    __syncthreads();
    int wv = threadIdx.x >> 6, lane = threadIdx.x & 63;
    int gm = blockIdx.x * 4 + wv;
    if (gm >= BB * MM) return;
    int b = gm / MM, m = gm - b * MM;
    const float4* cb4 = cand4 + b * NN;
    const float* db = data + b * NN * 3;
    float4 cen = cb4[3 * m];
    float cx = cen.x, cy = cen.y, cz = cen.z, sa = cen.w;

    // fast ball query: exact-d2 filter of the merged 10-NN
    int cnt;
    bool fallback;
    {
        float d2l = 1e30f;
        int idxl = 0;
        if (lane < 10) {
            uint32_t key = mrg[lane * (BB * NN) + b * NN + 3 * m];
            idxl = (int)(key & 0xFFFu);
            float4 c = cb4[idxl];
            float dot = fmaf(cz, c.z, fmaf(cy, c.y, cx * c.x));
            d2l = (sa + c.w) - 2.f * dot;
        }
        bool valid = (lane < 10) && (d2l < RAD2);
        unsigned long long mask = __ballot(valid);
        if (valid) sIdx[wv][__popcll(mask & ((1ull << lane) - 1ull))] = idxl;
        cnt = __popcll(mask);
        fallback = rl(d2l, 9) < RAD2 * 1.0005f;   // ball might exceed top-10
    }
    if (fallback) {
        cnt = 0;
        for (int base = 0; base < NN; base += 64) {
            int n = base + lane;
            float4 c = cb4[n];
            float dot = fmaf(cz, c.z, fmaf(cy, c.y, cx * c.x));
            float d2 = (sa + c.w) - 2.f * dot;
            bool valid = d2 < RAD2;
            unsigned long long mask = __ballot(valid);
            if (valid) {
                int pos = cnt + __popcll(mask & ((1ull << lane) - 1ull));
                if (pos < NS) sIdx[wv][pos] = n;
            }
            cnt += __popcll(mask);
            if (cnt >= NS) break;
        }
    }
    int scnt = cnt < NS ? cnt : NS;

    float cl = lane == 0 ? cx : (lane == 1 ? cy : cz);
    float hb0 = bsa[lane], hb1 = bsa[64 + lane];
    float m0 = 0.f, m1 = 0.f;       // relu outputs >= 0

    for (int s0 = 0; s0 < scnt; s0 += 4) {
        float fr[4], fr2[4];
        #pragma unroll
        for (int u = 0; u < 4; ++u) {
            int s = s0 + u;
            if (s >= scnt) s = 0;          // pad with sample 0 (real, max-safe)
            int nj = sIdx[wv][s];
            int fb = (b * NN + nj) * 64;
            float v;
            if (lane >= 3) v = f0[fb + lane - 3];
            else           v = (db[nj * 3 + lane] - cl) * 10.0f;   // dp = diff/0.1
            fr[u] = v;
            fr2[u] = (lane < 3) ? f0[fb + 61 + lane] : 0.f;
        }
        float h0[4], h1[4];
        #pragma unroll
        for (int u = 0; u < 4; ++u) { h0[u] = hb0; h1[u] = hb1; }
        for (int k = 0; k < 64; ++k) {
            float2 w = sW[k * 64 + lane];
            #pragma unroll
            for (int u = 0; u < 4; ++u) {
                float fv = rl(fr[u], k);
                h0[u] = fmaf(fv, w.x, h0[u]);
                h1[u] = fmaf(fv, w.y, h1[u]);
            }
        }
        #pragma unroll
        for (int k = 64; k < 67; ++k) {
            float2 w = sW[k * 64 + lane];
            #pragma unroll
            for (int u = 0; u < 4; ++u) {
                float fv = rl(fr2[u], k - 64);
                h0[u] = fmaf(fv, w.x, h0[u]);
                h1[u] = fmaf(fv, w.y, h1[u]);
            }
        }
        #pragma unroll
        for (int u = 0; u < 4; ++u) {
            m0 = fmaxf(m0, fmaxf(h0[u], 0.f));
            m1 = fmaxf(m1, fmaxf(h1[u], 0.f));
        }
    }
    fsub[gm * 128 + lane] = m0;
    fsub[gm * 128 + 64 + lane] = m1;
}

// ---------------- K4: 3-NN among centers + inverse-distance interp ----------------
__global__ __launch_bounds__(512) void k_interp(const float4* __restrict__ cand4,
                                                const float* __restrict__ fsub,
                                                float* __restrict__ itp) {
    __shared__ float4 sC[MM];
    __shared__ float sMD[8][64][3];
    __shared__ int   sMI[8][64][3];
    __shared__ float sWts[64][3];
    __shared__ int   sNbr[64][3];
    int t = threadIdx.x, wv = t >> 6, lane = t & 63;
    int blk = blockIdx.x;
    int b = blk >> 6;
    int pbase = (blk & 63) * 64;
    const float4* cb4 = cand4 + b * NN;
    for (int m = t; m < MM; m += 512) sC[m] = cb4[3 * m];
    __syncthreads();
    int p = pbase + lane;
    float4 pm = cb4[p];
    float px = pm.x, py = pm.y, pz = pm.z, pa = pm.w;
    float d0 = 1e30f, d1 = 1e30f, d2v = 1e30f;
    int n0 = 0, n1 = 0, n2 = 0;
    int ms = wv * 171, me = ms + 171 < MM ? ms + 171 : MM;
    for (int m = ms; m < me; ++m) {
        float4 c = sC[m];
        float dd = (pa + c.w) - 2.f * (px * c.x + py * c.y + pz * c.z);
        if (dd < d2v) {
            if (dd < d1) {
                d2v = d1; n2 = n1;
                if (dd < d0) { d1 = d0; n1 = n0; d0 = dd; n0 = m; }
                else         { d1 = dd; n1 = m; }
            } else { d2v = dd; n2 = m; }
        }
    }
    sMD[wv][lane][0] = d0; sMD[wv][lane][1] = d1; sMD[wv][lane][2] = d2v;
    sMI[wv][lane][0] = n0; sMI[wv][lane][1] = n1; sMI[wv][lane][2] = n2;
    __syncthreads();
    if (wv == 0) {
        d0 = sMD[0][lane][0]; d1 = sMD[0][lane][1]; d2v = sMD[0][lane][2];
        n0 = sMI[0][lane][0]; n1 = sMI[0][lane][1]; n2 = sMI[0][lane][2];
        for (int w = 1; w < 8; ++w) {
            #pragma unroll
            for (int r = 0; r < 3; ++r) {
                float dd = sMD[w][lane][r];
                int mm = sMI[w][lane][r];
                if (dd < d2v) {
                    if (dd < d1) {
                        d2v = d1; n2 = n1;
                        if (dd < d0) { d1 = d0; n1 = n0; d0 = dd; n0 = mm; }
                        else         { d1 = dd; n1 = mm; }
                    } else { d2v = dd; n2 = mm; }
                }
            }
        }
        float w0 = 1.f / (d0 + 1e-8f), w1 = 1.f / (d1 + 1e-8f), w2 = 1.f / (d2v + 1e-8f);
        float ws = w0 + w1 + w2;
        sWts[lane][0] = w0 / ws; sWts[lane][1] = w1 / ws; sWts[lane][2] = w2 / ws;
        sNbr[lane][0] = n0; sNbr[lane][1] = n1; sNbr[lane][2] = n2;
    }
    __syncthreads();
    for (int i = wv * 8; i < wv * 8 + 8; ++i) {
        float a0 = sWts[i][0], a1 = sWts[i][1], a2 = sWts[i][2];
        const float* r0 = fsub + (b * MM + sNbr[i][0]) * 128;
        const float* r1 = fsub + (b * MM + sNbr[i][1]) * 128;
        const float* r2 = fsub + (b * MM + sNbr[i][2]) * 128;
        float v0 = fmaf(a2, r2[lane], fmaf(a1, r1[lane], a0 * r0[lane]));
        float v1 = fmaf(a2, r2[64 + lane], fmaf(a1, r1[64 + lane], a0 * r0[64 + lane]));
        int row = b * NN + pbase + i;
        itp[row * 128 + lane] = v0;
        itp[row * 128 + 64 + lane] = v1;
    }
}

// ---------------- K5: f = relu([interp, f0] @ W_fp + b_fp) ----------------
__global__ __launch_bounds__(256) void k_fp(const float* __restrict__ itp,
                                            const float* __restrict__ f0,
                                            const float* __restrict__ W,
                                            const float* __restrict__ bias,
                                            float* __restrict__ outf) {
    __shared__ float sW[192 * 64];
    for (int i = threadIdx.x; i < 192 * 64; i += 256) sW[i] = W[i];
    __syncthreads();
    int lane = threadIdx.x & 63;
    int wv = threadIdx.x >> 6;
    float bb = bias[lane];
    int rowbase = blockIdx.x * 64 + wv * 16;
    for (int it = 0; it < 4; ++it) {
        int r = rowbase + it * 4;
        float fa[4], fbv[4], fc[4], acc[4];
        #pragma unroll
        for (int u = 0; u < 4; ++u) {
            fa[u]  = itp[(r + u) * 128 + lane];
            fbv[u] = itp[(r + u) * 128 + 64 + lane];
            fc[u]  = f0[(r + u) * 64 + lane];
            acc[u] = bb;
        }
        #pragma unroll
        for (int k = 0; k < 192; ++k) {
            float w = sW[k * 64 + lane];
            #pragma unroll
            for (int u = 0; u < 4; ++u) {
                float fv = k < 64 ? rl(fa[u], k)
                         : (k < 128 ? rl(fbv[u], k - 64) : rl(fc[u], k - 128));
                acc[u] = fmaf(fv, w, acc[u]);
            }
        }
        #pragma unroll
        for (int u = 0; u < 4; ++u)
            outf[(r + u) * 64 + lane] = fmaxf(acc[u], 0.f);
    }
}

// ---------------- K6: zc = [f, ef] @ W_fin + b_fin ----------------
__global__ __launch_bounds__(256) void k_fin(const float* __restrict__ fb,
                                             const float* __restrict__ efb,
                                             const float* __restrict__ W,
                                             const float* __restrict__ bias,
                                             float* __restrict__ zc) {
    __shared__ float sW[68 * 64];
    for (int i = threadIdx.x; i < 68 * 64; i += 256) sW[i] = W[i];
    __syncthreads();
    int lane = threadIdx.x & 63;
    int wv = threadIdx.x >> 6;
    float bb = bias[lane];
    int rowbase = blockIdx.x * 64 + wv * 16;
    for (int it = 0; it < 4; ++it) {
        int r = rowbase + it * 4;
        float fa[4], fe[4], acc[4];
        #pragma unroll
        for (int u = 0; u < 4; ++u) {
            fa[u] = fb[(r + u) * 64 + lane];
            fe[u] = (lane < 4) ? efb[(r + u) * 4 + lane] : 0.f;
            acc[u] = bb;
        }
        #pragma unroll
        for (int k = 0; k < 68; ++k) {
            float w = sW[k * 64 + lane];
            #pragma unroll
            for (int u = 0; u < 4; ++u) {
                float fv = k < 64 ? rl(fa[u], k) : rl(fe[u], k - 64);
                acc[u] = fmaf(fv, w, acc[u]);
            }
        }
        #pragma unroll
        for (int u = 0; u < 4; ++u)
            zc[(r + u) * 64 + lane] = acc[u];
    }
}

// ---------------- K7: batchnorm stats, two-stage ----------------
__global__ __launch_bounds__(256) void k_stats1(const float* __restrict__ zc,
                                                float* __restrict__ pp) {
    int t = threadIdx.x;
    int c = t & 63, r4 = t >> 6;
    float s = 0.f, sq = 0.f;
    int base = blockIdx.x * 512;
    for (int i = 0; i < 128; ++i) {
        float v = zc[(base + i * 4 + r4) * 64 + c];
        s += v;
        sq = fmaf(v, v, sq);
    }
    __shared__ float ls[256], lq[256];
    ls[t] = s; lq[t] = sq;
    __syncthreads();
    if (t < 64) {
        float st = ls[t] + ls[t + 64] + ls[t + 128] + ls[t + 192];
        float qt = lq[t] + lq[t + 64] + lq[t + 128] + lq[t + 192];
        pp[blockIdx.x * 128 + t] = st;
        pp[blockIdx.x * 128 + 64 + t] = qt;
    }
}

__global__ __launch_bounds__(64) void k_stats2(const float* __restrict__ pp,
                                               const float* __restrict__ gamma,
                                               const float* __restrict__ beta,
                                               float* __restrict__ ss) {
    int c = threadIdx.x;
    float s = 0.f, sq = 0.f;
    for (int k = 0; k < 64; ++k) {
        s += pp[k * 128 + c];
        sq += pp[k * 128 + 64 + c];
    }
    const float inv = 1.f / (float)(BB * NN);
    float mu = s * inv;
    float var = sq * inv - mu * mu;
    float sc = gamma[c] / sqrtf(var + 1e-5f);
    ss[c] = sc;
    ss[64 + c] = beta[c] - mu * sc;
}

// ---------------- K8: normalize + relu + transpose ----------------
__global__ __launch_bounds__(256) void k_norm_t(const float* __restrict__ zc,
                                                const float* __restrict__ ss,
                                                float* __restrict__ out) {
    __shared__ float sT[64][65];
    int blk = blockIdx.x;
    int b = blk >> 6;
    int nbase = (blk & 63) * 64;
    int c = threadIdx.x & 63;
    int r4 = threadIdx.x >> 6;
    float sc = ss[c], sh = ss[64 + c];
    #pragma unroll
    for (int i = 0; i < 16; ++i) {
        int nr = i * 4 + r4;
        float v = zc[(b * NN + nbase + nr) * 64 + c];
        sT[nr][c] = fmaxf(fmaf(v, sc, sh), 0.f);
    }
    __syncthreads();
    int nn = threadIdx.x & 63;
    #pragma unroll
    for (int i = 0; i < 16; ++i) {
        int cc = i * 4 + r4;
        out[BB * NN * 3 + (b * 64 + cc) * NN + nbase + nn] = sT[nn][cc];
    }
}

extern "C" void kernel_launch(void* const* d_in, const int* in_sizes, int n_in,
                              void* d_out, int out_size, void* d_ws, size_t ws_size,
                              hipStream_t stream) {
    const float* data = (const float*)d_in[0];
    const float* Wst  = (const float*)d_in[2];
    const float* bst  = (const float*)d_in[3];
    const float* Wsa  = (const float*)d_in[4];
    const float* bsa  = (const float*)d_in[5];
    const float* Wfp  = (const float*)d_in[6];
    const float* bfp  = (const float*)d_in[7];
    const float* We1  = (const float*)d_in[8];
    const float* be1  = (const float*)d_in[9];
    const float* We2  = (const float*)d_in[10];
    const float* be2  = (const float*)d_in[11];
    const float* Wfin = (const float*)d_in[12];
    const float* bfin = (const float*)d_in[13];
    const float* gamma = (const float*)d_in[14];
    const float* beta  = (const float*)d_in[15];
    float* out = (float*)d_out;

    // layout (floats): buffers consumed late come last so scratch can alias them
    float* f0   = (float*)d_ws;            // 2,097,152
    float* fsub = f0 + 2097152;            // 1,398,784
    float* efb  = fsub + 1398784;          //   131,072
    float* zc   = efb + 131072;            // 2,097,152
    float* ss   = zc + 2097152;            //       128
    float* pp   = ss + 128;                //     8,192
    float4* cand4 = (float4*)(pp + 8192);  //   131,072 floats, 16B-aligned
    uint32_t* mrgb = (uint32_t*)((float*)cand4 + 131072);   // 1,310,720 u32 region
    float* itp  = (float*)mrgb + 1310720;  // 4,194,304
    float* fb   = itp + 4194304;           // 2,097,152
    // sort scratch (cand4s 131,072 + perm 32,768 + gbox 4,096 words) aliases itp:
    // fully consumed by k_knn before k_interp writes itp.
    float4*   cand4s = (float4*)itp;
    uint32_t* perm   = (uint32_t*)(itp + 131072);
    float4*   gbox   = (float4*)(itp + 131072 + 32768);

    // stem grid: 8192 stem blocks + 128 prep blocks (block-level split)
    k_stem<<<(BB * NN * 64) / 256 + (BB * NN) / 256, 256, 0, stream>>>(
        data, Wst, bst, f0, out, cand4);
    k_sort<<<BB, 256, 0, stream>>>(cand4, cand4s, perm, gbox);
    k_knn<<<BB * NGRP, 256, 0, stream>>>(cand4s, perm, gbox, mrgb);
    k_knn_eig<<<(BB * NN) / 256, 256, 0, stream>>>(cand4, mrgb, We1, be1, We2, be2, efb);
    k_sa<<<(BB * MM + 3) / 4, 256, 0, stream>>>(cand4, data, f0, mrgb, Wsa, bsa, fsub);
    k_interp<<<BB * 64, 512, 0, stream>>>(cand4, fsub, itp);
    k_fp<<<512, 256, 0, stream>>>(itp, f0, Wfp, bfp, fb);
    k_fin<<<512, 256, 0, stream>>>(fb, efb, Wfin, bfin, zc);
    k_stats1<<<64, 256, 0, stream>>>(zc, pp);
    k_stats2<<<1, 64, 0, stream>>>(pp, gamma, beta, ss);
    k_norm_t<<<512, 256, 0, stream>>>(zc, ss, out);
}

// Round 7
// 317.832 us; speedup vs baseline: 1.0783x; 1.0576x over previous
//
#include <hip/hip_runtime.h>
#include <stdint.h>

#define BB 8
#define NN 4096
#define MM 1366   // len(arange(0,4096,3))
#define NS 32
#define RAD2 0.01f
#define NGRP 64          // groups of 64 sorted points per batch
#define KW 8             // waves per k_knn block

__device__ __forceinline__ float rl(float v, int l) {
    return __int_as_float(__builtin_amdgcn_readlane(__float_as_int(v), l));
}
__device__ __forceinline__ uint32_t um(uint32_t a, uint32_t b) { return a < b ? a : b; }
__device__ __forceinline__ uint32_t ux(uint32_t a, uint32_t b) { return a > b ? a : b; }
__device__ __forceinline__ uint32_t um3(uint32_t a, uint32_t b, uint32_t c) { return um(um(a, b), c); }

// merge sorted pair (s0<=s1) into sorted-10 kk
__device__ __forceinline__ void mrg2(uint32_t* kk, uint32_t s0, uint32_t s1) {
    uint32_t n0 = um(kk[0], s0);
    uint32_t n1 = um3(kk[1], ux(kk[0], s0), s1);
    uint32_t n2 = um3(kk[2], ux(kk[1], s0), ux(kk[0], s1));
    uint32_t n3 = um3(kk[3], ux(kk[2], s0), ux(kk[1], s1));
    uint32_t n4 = um3(kk[4], ux(kk[3], s0), ux(kk[2], s1));
    uint32_t n5 = um3(kk[5], ux(kk[4], s0), ux(kk[3], s1));
    uint32_t n6 = um3(kk[6], ux(kk[5], s0), ux(kk[4], s1));
    uint32_t n7 = um3(kk[7], ux(kk[6], s0), ux(kk[5], s1));
    uint32_t n8 = um3(kk[8], ux(kk[7], s0), ux(kk[6], s1));
    uint32_t n9 = um3(kk[9], ux(kk[8], s0), ux(kk[7], s1));
    kk[0]=n0; kk[1]=n1; kk[2]=n2; kk[3]=n3; kk[4]=n4;
    kk[5]=n5; kk[6]=n6; kk[7]=n7; kk[8]=n8; kk[9]=n9;
}

// merge sorted quad (s0<=s1<=s2<=s3) into sorted-10 kk
__device__ __forceinline__ void mrg4(uint32_t* kk, uint32_t s0, uint32_t s1,
                                     uint32_t s2, uint32_t s3) {
    uint32_t n0 = um(kk[0], s0);
    uint32_t n1 = um3(kk[1], ux(kk[0], s0), s1);
    uint32_t n2 = um(um3(kk[2], ux(kk[1], s0), ux(kk[0], s1)), s2);
    uint32_t n3 = um3(um3(kk[3], ux(kk[2], s0), ux(kk[1], s1)), ux(kk[0], s2), s3);
    uint32_t n4 = um3(um3(kk[4], ux(kk[3], s0), ux(kk[2], s1)), ux(kk[1], s2), ux(kk[0], s3));
    uint32_t n5 = um3(um3(kk[5], ux(kk[4], s0), ux(kk[3], s1)), ux(kk[2], s2), ux(kk[1], s3));
    uint32_t n6 = um3(um3(kk[6], ux(kk[5], s0), ux(kk[4], s1)), ux(kk[3], s2), ux(kk[2], s3));
    uint32_t n7 = um3(um3(kk[7], ux(kk[6], s0), ux(kk[5], s1)), ux(kk[4], s2), ux(kk[3], s3));
    uint32_t n8 = um3(um3(kk[8], ux(kk[7], s0), ux(kk[6], s1)), ux(kk[5], s2), ux(kk[4], s3));
    uint32_t n9 = um3(um3(kk[9], ux(kk[8], s0), ux(kk[7], s1)), ux(kk[6], s2), ux(kk[5], s3));
    kk[0]=n0; kk[1]=n1; kk[2]=n2; kk[3]=n3; kk[4]=n4;
    kk[5]=n5; kk[6]=n6; kk[7]=n7; kk[8]=n8; kk[9]=n9;
}

// sort 4 keys ascending: 5-CE network
__device__ __forceinline__ void srt4(uint32_t& a, uint32_t& b, uint32_t& c, uint32_t& d) {
    uint32_t t0 = um(a, b), t1 = ux(a, b), t2 = um(c, d), t3 = ux(c, d);
    uint32_t s0 = um(t0, t2), m0 = ux(t0, t2), m1 = um(t1, t3), s3 = ux(t1, t3);
    a = s0; b = um(m0, m1); c = ux(m0, m1); d = s3;
}

// spread 4 bits to every 3rd bit position (0,3,6,9)
__device__ __forceinline__ uint32_t spr3(uint32_t v) {
    v = (v | (v << 4)) & 0xC3u;
    v = (v | (v << 2)) & 0x249u;
    return v;
}

// ---------------- K1: stem (+ prep absorbed as extra blocks) ----------------
__global__ __launch_bounds__(256) void k_stem(const float* __restrict__ data,
                                              const float* __restrict__ Ws,
                                              const float* __restrict__ bs,
                                              float* __restrict__ f0,
                                              float* __restrict__ out,
                                              float4* __restrict__ cand4) {
    int blk = blockIdx.x;
    if (blk >= (BB * NN * 64) / 256) {
        // prep blocks: copy data -> out, build cand4 = (x,y,z,|p|^2)
        int t = (blk - (BB * NN * 64) / 256) * 256 + threadIdx.x;   // BB*NN
        float x = data[t * 3], y = data[t * 3 + 1], z = data[t * 3 + 2];
        out[t * 3] = x; out[t * 3 + 1] = y; out[t * 3 + 2] = z;
        cand4[t] = make_float4(x, y, z, x * x + y * y + z * z);
        return;
    }
    int t = blk * 256 + threadIdx.x;
    int c = t & 63;
    int r = t >> 6;
    const float* d = data + r * 3;
    float acc = bs[c];
    acc = fmaf(d[0], Ws[c], acc);
    acc = fmaf(d[1], Ws[64 + c], acc);
    acc = fmaf(d[2], Ws[128 + c], acc);
    f0[t] = fmaxf(acc, 0.f);
}

// ---------------- K1b: Morton counting-sort of each batch + per-group bboxes ----------------
__global__ __launch_bounds__(256) void k_sort(const float4* __restrict__ cand4,
                                              float4* __restrict__ cand4s,
                                              uint32_t* __restrict__ perm,
                                              float4* __restrict__ gbox) {
    __shared__ uint32_t cnt[4096];   // 16^3 Morton cells
    __shared__ uint32_t part[256];
    int b = blockIdx.x, t = threadIdx.x;
    const float4* cb = cand4 + b * NN;
    for (int i = t; i < 4096; i += 256) cnt[i] = 0;
    __syncthreads();
    uint32_t cid[16];
    #pragma unroll
    for (int u = 0; u < 16; ++u) {
        float4 c = cb[u * 256 + t];
        int ix = (int)floorf((c.x + 4.f) * 2.f);
        int iy = (int)floorf((c.y + 4.f) * 2.f);
        int iz = (int)floorf((c.z + 4.f) * 2.f);
        ix = ix < 0 ? 0 : (ix > 15 ? 15 : ix);
        iy = iy < 0 ? 0 : (iy > 15 ? 15 : iy);
        iz = iz < 0 ? 0 : (iz > 15 ? 15 : iz);
        uint32_t m = spr3((uint32_t)ix) | (spr3((uint32_t)iy) << 1) | (spr3((uint32_t)iz) << 2);
        cid[u] = m;
        atomicAdd(&cnt[m], 1u);
    }
    __syncthreads();
    // prefix sum over 4096 bins: 16 serial per thread + block scan of 256
    uint32_t c16[16];
    uint32_t s = 0;
    #pragma unroll
    for (int u = 0; u < 16; ++u) { c16[u] = cnt[t * 16 + u]; s += c16[u]; }
    part[t] = s;
    __syncthreads();
    for (int off = 1; off < 256; off <<= 1) {
        uint32_t v = (t >= off) ? part[t - off] : 0u;
        __syncthreads();
        part[t] += v;
        __syncthreads();
    }
    uint32_t run = part[t] - s;   // exclusive prefix of this thread's 16 bins
    #pragma unroll
    for (int u = 0; u < 16; ++u) { cnt[t * 16 + u] = run; run += c16[u]; }
    __syncthreads();
    // scatter (order within cell irrelevant: selection later is an exact total order)
    #pragma unroll
    for (int u = 0; u < 16; ++u) {
        int p = u * 256 + t;
        uint32_t pos = atomicAdd(&cnt[cid[u]], 1u);
        cand4s[b * NN + pos] = cb[p];
        perm[b * NN + pos] = (uint32_t)p;   // 12-bit local original index
    }
    __syncthreads();   // drains vmcnt: our global writes are visible to our reads below
    // per-group (64 sorted points) bounding boxes
    if (t < NGRP) {
        float4 mn = make_float4(1e30f, 1e30f, 1e30f, 0.f);
        float4 mx = make_float4(-1e30f, -1e30f, -1e30f, 0.f);
        for (int j = 0; j < 64; ++j) {
            float4 c = cand4s[b * NN + t * 64 + j];
            mn.x = fminf(mn.x, c.x); mn.y = fminf(mn.y, c.y); mn.z = fminf(mn.z, c.z);
            mx.x = fmaxf(mx.x, c.x); mx.y = fmaxf(mx.y, c.y); mx.z = fmaxf(mx.z, c.z);
        }
        gbox[(b * NGRP + t) * 2]     = mn;
        gbox[(b * NGRP + t) * 2 + 1] = mx;
    }
}

// ---------------- K2: exact top-10 NN, PER-LANE a-priori home bound ----------------
// Block = query group g (8 waves). Every wave scans the home group (64 sorted
// neighbors); each LANE keeps its own bound thrK = home-10th-key + 1ulp (valid a
// priori: true10 <= home10). Waves 1..7 reset their lists (g's keys live only in
// wave0's list -> no dups) and scan a stride-8 slice of the other 63 groups, gated
// per-lane by point-box lower bound vs float(min(kk[9], thrK)) and per-packet
// ballot vs min(kk[9], thrK). Exact per lane l: any final top-10 member of l has
// key < true10(l) <= home10(l) < thrK(l), so l's gate and ballot pass in the unique
// wave owning that group. One barrier, one 7-list merge, no cross-wave scheduling.
__global__ __launch_bounds__(512) void k_knn(const float4* __restrict__ cand4s,
                                             const uint32_t* __restrict__ perm,
                                             const float4* __restrict__ gbox,
                                             uint32_t* __restrict__ mrg) {
    __shared__ float4 sBox[2 * NGRP];
    __shared__ uint32_t sKK[KW - 1][64][10];
    int t = threadIdx.x, w = t >> 6, lane = t & 63;
    int gw = blockIdx.x;           // global group id 0..511
    int b = gw >> 6;
    int g = gw & (NGRP - 1);
    for (int i = t; i < 2 * NGRP; i += 512) sBox[i] = gbox[b * 2 * NGRP + i];
    __syncthreads();
    const float4* cs = cand4s + b * NN;
    const uint32_t* ps = perm + b * NN;
    float4 me = cs[g * 64 + lane];
    uint32_t mo = ps[g * 64 + lane];
    float px = me.x, py = me.y, pz = me.z, pa = me.w;
    uint32_t kk[10];
    #pragma unroll
    for (int r = 0; r < 10; ++r) kk[r] = 0xFFFFFF00u + r;   // ascending sentinels

    auto scan_packets = [&](int jg, uint32_t thrC) {
        const float4* cp = cs + jg * 64;
        const uint4* pq = (const uint4*)(ps + jg * 64);
        uint32_t thr = um(kk[9], thrC);
        for (int j = 0; j < 16; ++j) {
            float4 ca  = cp[j * 4];
            float4 cbv = cp[j * 4 + 1];
            float4 cc  = cp[j * 4 + 2];
            float4 cd  = cp[j * 4 + 3];
            uint4 pm = pq[j];
            float da  = fmaxf(fmaf(-2.f, fmaf(pz, ca.z,  fmaf(py, ca.y,  px * ca.x)),  pa + ca.w),  0.f);
            float db_ = fmaxf(fmaf(-2.f, fmaf(pz, cbv.z, fmaf(py, cbv.y, px * cbv.x)), pa + cbv.w), 0.f);
            float dc  = fmaxf(fmaf(-2.f, fmaf(pz, cc.z,  fmaf(py, cc.y,  px * cc.x)),  pa + cc.w),  0.f);
            float dd  = fmaxf(fmaf(-2.f, fmaf(pz, cd.z,  fmaf(py, cd.y,  px * cd.x)),  pa + cd.w),  0.f);
            uint32_t ka = (__float_as_uint(da)  & 0xFFFFF000u) | pm.x;
            uint32_t kb = (__float_as_uint(db_) & 0xFFFFF000u) | pm.y;
            uint32_t kc = (__float_as_uint(dc)  & 0xFFFFF000u) | pm.z;
            uint32_t kd = (__float_as_uint(dd)  & 0xFFFFF000u) | pm.w;
            uint32_t mn4 = um(um(ka, kb), um(kc, kd));
            if (__ballot(mn4 < thr)) {       // wave-uniform: skip if nobody can improve
                srt4(ka, kb, kc, kd);
                mrg4(kk, ka, kb, kc, kd);
                thr = um(kk[9], thrC);
            }
        }
    };

    scan_packets(g, 0xFFFFFFFFu);            // full home scan (every wave, redundant)

    // PER-LANE a-priori bound key: home 10th key +1 ulp (20-bit), index bits zeroed.
    // Home group has 64 real candidates -> kk[9] is real, no sentinel overflow.
    uint32_t thrK = (kk[9] & 0xFFFFF000u) + 0x1000u;

    if (w > 0) {                             // reset: g's keys only in wave0's list
        #pragma unroll
        for (int r = 0; r < 10; ++r) kk[r] = 0xFFFFFF00u + r;
    }

    for (int jg = w; jg < NGRP; jg += KW) {
        if (jg == g) continue;
        float4 bmn = sBox[jg * 2], bmx = sBox[jg * 2 + 1];
        float dx = fmaxf(fmaxf(bmn.x - px, px - bmx.x), 0.f);
        float dy = fmaxf(fmaxf(bmn.y - py, py - bmx.y), 0.f);
        float dz = fmaxf(fmaxf(bmn.z - pz, pz - bmx.z), 0.f);
        float lb = fmaf(dx, dx, fmaf(dy, dy, dz * dz));
        uint32_t mt = um(kk[9], thrK);       // per-lane threshold (monotone <= thrK)
        float tf = __uint_as_float((mt & 0xFFFFF000u) + 0x1000u) * 1.0005f;
        if (__ballot(lb < tf))               // any lane could improve -> scan group
            scan_packets(jg, thrK);
    }

    if (w > 0) {
        #pragma unroll
        for (int r = 0; r < 10; ++r) sKK[w - 1][lane][r] = kk[r];
    }
    __syncthreads();
    if (w == 0) {
        for (int ww = 0; ww < KW - 1; ++ww) {
            uint32_t s[10];
            #pragma unroll
            for (int r = 0; r < 10; ++r) s[r] = sKK[ww][lane][r];
            mrg4(kk, s[0], s[1], s[2], s[3]);
            mrg4(kk, s[4], s[5], s[6], s[7]);
            mrg2(kk, s[8], s[9]);
        }
        int gp = b * NN + (int)mo;
        #pragma unroll
        for (int r = 0; r < 10; ++r) mrg[r * (BB * NN) + gp] = kk[r];
    }
}

// ---------------- K2b: cov, Jacobi eig, eig-MLP from merged 10-NN ----------------
__device__ __forceinline__ void jrot(float& app, float& aqq, float& apq,
                                     float& arp, float& arq) {
    float ap = apq;
    if (fabsf(ap) > 1e-32f) {
        float th = (aqq - app) / (2.f * ap);
        float t = 1.f / (fabsf(th) + sqrtf(th * th + 1.f));
        t = th < 0.f ? -t : t;
        float c = 1.f / sqrtf(t * t + 1.f);
        float s = t * c;
        app = app - t * ap;
        aqq = aqq + t * ap;
        apq = 0.f;
        float rp = arp, rq = arq;
        arp = c * rp - s * rq;
        arq = s * rp + c * rq;
    }
}

__global__ __launch_bounds__(256) void k_knn_eig(const float4* __restrict__ cand4,
                                                 const uint32_t* __restrict__ mrg,
                                                 const float* __restrict__ We1,
                                                 const float* __restrict__ be1,
                                                 const float* __restrict__ We2,
                                                 const float* __restrict__ be2,
                                                 float* __restrict__ ef) {
    int t = blockIdx.x * 256 + threadIdx.x;   // B*N
    int b = t >> 12;
    const float4* cb = cand4 + b * NN;
    uint32_t kk[10];
    #pragma unroll
    for (int r = 0; r < 10; ++r) kk[r] = mrg[r * (BB * NN) + t];
    float xs[10], ys[10], zs[10];
    float mx = 0.f, my = 0.f, mz = 0.f;
    #pragma unroll
    for (int r = 0; r < 10; ++r) {
        int n = (int)(kk[r] & 0xFFFu);
        float4 cr = cb[n];
        xs[r] = cr.x; ys[r] = cr.y; zs[r] = cr.z;
        mx += xs[r]; my += ys[r]; mz += zs[r];
    }
    mx *= 0.1f; my *= 0.1f; mz *= 0.1f;
    float a00 = 0, a01 = 0, a02 = 0, a11 = 0, a12 = 0, a22 = 0;
    #pragma unroll
    for (int r = 0; r < 10; ++r) {
        float x = xs[r] - mx, y = ys[r] - my, z = zs[r] - mz;
        a00 = fmaf(x, x, a00); a01 = fmaf(x, y, a01); a02 = fmaf(x, z, a02);
        a11 = fmaf(y, y, a11); a12 = fmaf(y, z, a12); a22 = fmaf(z, z, a22);
    }
    a00 *= 0.1f; a01 *= 0.1f; a02 *= 0.1f; a11 *= 0.1f; a12 *= 0.1f; a22 *= 0.1f;
    #pragma unroll
    for (int sweep = 0; sweep < 6; ++sweep) {
        jrot(a00, a11, a01, a02, a12);
        jrot(a00, a22, a02, a01, a12);
        jrot(a11, a22, a12, a01, a02);
    }
    float e0 = a00, e1 = a11, e2 = a22, tmp;
    if (e0 > e1) { tmp = e0; e0 = e1; e1 = tmp; }
    if (e1 > e2) { tmp = e1; e1 = e2; e2 = tmp; }
    if (e0 > e1) { tmp = e0; e0 = e1; e1 = tmp; }
    float tt[4];
    #pragma unroll
    for (int i = 0; i < 4; ++i) {
        float v = be1[i];
        v = fmaf(e0, We1[i], v);
        v = fmaf(e1, We1[4 + i], v);
        v = fmaf(e2, We1[8 + i], v);
        tt[i] = fmaxf(v, 0.f);
    }
    #pragma unroll
    for (int i = 0; i < 4; ++i) {
        float v = be2[i];
        v = fmaf(tt[0], We2[i], v);
        v = fmaf(tt[1], We2[4 + i], v);
        v = fmaf(tt[2], We2[8 + i], v);
        v = fmaf(tt[3], We2[12 + i], v);
        ef[t * 4 + i] = v;
    }
}

// ---------------- K3: ball query (via merged 10-NN) + SA MLP + maxpool ----------------
__global__ __launch_bounds__(256) void k_sa(const float4* __restrict__ cand4,
                                            const float* __restrict__ data,
                                            const float* __restrict__ f0,
                                            const uint32_t* __restrict__ mrg,
                                            const float* __restrict__ Wsa,
                                            const float* __restrict__ bsa,
                                            float* __restrict__ fsub) {
    __shared__ float2 sW[67 * 64];
    __shared__ int sIdx[4][NS];
    for (int i = threadIdx.x; i < 67 * 64; i += 256) {
        int k = i >> 6, c = i & 63;
        sW[i] = make_float2(Wsa[k * 128 + c], Wsa[k * 128 + 64 + c]);
    }
    __syncthreads();
    int wv = threadIdx.x >> 6, lane = threadIdx.x & 63;
    int gm = blockIdx.x * 4 + wv;
    if (gm >= BB * MM) return;
    int b = gm / MM, m = gm - b * MM;
    const float4* cb4 = cand4 + b * NN;
    const float* db = data + b * NN * 3;
    float4 cen = cb4[3 * m];
    float cx = cen.x, cy = cen.y, cz = cen.z, sa = cen.w;

    // fast ball query: exact-d2 filter of the merged 10-NN
    int cnt;
    bool fallback;
    {
        float d2l = 1e30f;
        int idxl = 0;
        if (lane < 10) {
            uint32_t key = mrg[lane * (BB * NN) + b * NN + 3 * m];
            idxl = (int)(key & 0xFFFu);
            float4 c = cb4[idxl];
            float dot = fmaf(cz, c.z, fmaf(cy, c.y, cx * c.x));
            d2l = (sa + c.w) - 2.f * dot;
        }
        bool valid = (lane < 10) && (d2l < RAD2);
        unsigned long long mask = __ballot(valid);
        if (valid) sIdx[wv][__popcll(mask & ((1ull << lane) - 1ull))] = idxl;
        cnt = __popcll(mask);
        fallback = rl(d2l, 9) < RAD2 * 1.0005f;   // ball might exceed top-10
    }
    if (fallback) {
        cnt = 0;
        for (int base = 0; base < NN; base += 64) {
            int n = base + lane;
            float4 c = cb4[n];
            float dot = fmaf(cz, c.z, fmaf(cy, c.y, cx * c.x));
            float d2 = (sa + c.w) - 2.f * dot;
            bool valid = d2 < RAD2;
            unsigned long long mask = __ballot(valid);
            if (valid) {
                int pos = cnt + __popcll(mask & ((1ull << lane) - 1ull));
                if (pos < NS) sIdx[wv][pos] = n;
            }
            cnt += __popcll(mask);
            if (cnt >= NS) break;
        }
    }
    int scnt = cnt < NS ? cnt : NS;

    float cl = lane == 0 ? cx : (lane == 1 ? cy : cz);
    float hb0 = bsa[lane], hb1 = bsa[64 + lane];
    float m0 = 0.f, m1 = 0.f;       // relu outputs >= 0

    for (int s0 = 0; s0 < scnt; s0 += 4) {
        float fr[4], fr2[4];
        #pragma unroll
        for (int u = 0; u < 4; ++u) {
            int s = s0 + u;
            if (s >= scnt) s = 0;          // pad with sample 0 (real, max-safe)
            int nj = sIdx[wv][s];
            int fb = (b * NN + nj) * 64;
            float v;
            if (lane >= 3) v = f0[fb + lane - 3];
            else           v = (db[nj * 3 + lane] - cl) * 10.0f;   // dp = diff/0.1
            fr[u] = v;
            fr2[u] = (lane < 3) ? f0[fb + 61 + lane] : 0.f;
        }
        float h0[4], h1[4];
        #pragma unroll
        for (int u = 0; u < 4; ++u) { h0[u] = hb0; h1[u] = hb1; }
        for (int k = 0; k < 64; ++k) {
            float2 w = sW[k * 64 + lane];
            #pragma unroll
            for (int u = 0; u < 4; ++u) {
                float fv = rl(fr[u], k);
                h0[u] = fmaf(fv, w.x, h0[u]);
                h1[u] = fmaf(fv, w.y, h1[u]);
            }
        }
        #pragma unroll
        for (int k = 64; k < 67; ++k) {
            float2 w = sW[k * 64 + lane];
            #pragma unroll
            for (int u = 0; u < 4; ++u) {
                float fv = rl(fr2[u], k - 64);
                h0[u] = fmaf(fv, w.x, h0[u]);
                h1[u] = fmaf(fv, w.y, h1[u]);
            }
        }
        #pragma unroll
        for (int u = 0; u < 4; ++u) {
            m0 = fmaxf(m0, fmaxf(h0[u], 0.f));
            m1 = fmaxf(m1, fmaxf(h1[u], 0.f));
        }
    }
    fsub[gm * 128 + lane] = m0;
    fsub[gm * 128 + 64 + lane] = m1;
}

// ---------------- K4: 3-NN among centers + inverse-distance interp ----------------
__global__ __launch_bounds__(512) void k_interp(const float4* __restrict__ cand4,
                                                const float* __restrict__ fsub,
                                                float* __restrict__ itp) {
    __shared__ float4 sC[MM];
    __shared__ float sMD[8][64][3];
    __shared__ int   sMI[8][64][3];
    __shared__ float sWts[64][3];
    __shared__ int   sNbr[64][3];
    int t = threadIdx.x, wv = t >> 6, lane = t & 63;
    int blk = blockIdx.x;
    int b = blk >> 6;
    int pbase = (blk & 63) * 64;
    const float4* cb4 = cand4 + b * NN;
    for (int m = t; m < MM; m += 512) sC[m] = cb4[3 * m];
    __syncthreads();
    int p = pbase + lane;
    float4 pm = cb4[p];
    float px = pm.x, py = pm.y, pz = pm.z, pa = pm.w;
    float d0 = 1e30f, d1 = 1e30f, d2v = 1e30f;
    int n0 = 0, n1 = 0, n2 = 0;
    int ms = wv * 171, me = ms + 171 < MM ? ms + 171 : MM;
    for (int m = ms; m < me; ++m) {
        float4 c = sC[m];
        float dd = (pa + c.w) - 2.f * (px * c.x + py * c.y + pz * c.z);
        if (dd < d2v) {
            if (dd < d1) {
                d2v = d1; n2 = n1;
                if (dd < d0) { d1 = d0; n1 = n0; d0 = dd; n0 = m; }
                else         { d1 = dd; n1 = m; }
            } else { d2v = dd; n2 = m; }
        }
    }
    sMD[wv][lane][0] = d0; sMD[wv][lane][1] = d1; sMD[wv][lane][2] = d2v;
    sMI[wv][lane][0] = n0; sMI[wv][lane][1] = n1; sMI[wv][lane][2] = n2;
    __syncthreads();
    if (wv == 0) {
        d0 = sMD[0][lane][0]; d1 = sMD[0][lane][1]; d2v = sMD[0][lane][2];
        n0 = sMI[0][lane][0]; n1 = sMI[0][lane][1]; n2 = sMI[0][lane][2];
        for (int w = 1; w < 8; ++w) {
            #pragma unroll
            for (int r = 0; r < 3; ++r) {
                float dd = sMD[w][lane][r];
                int mm = sMI[w][lane][r];
                if (dd < d2v) {
                    if (dd < d1) {
                        d2v = d1; n2 = n1;
                        if (dd < d0) { d1 = d0; n1 = n0; d0 = dd; n0 = mm; }
                        else         { d1 = dd; n1 = mm; }
                    } else { d2v = dd; n2 = mm; }
                }
            }
        }
        float w0 = 1.f / (d0 + 1e-8f), w1 = 1.f / (d1 + 1e-8f), w2 = 1.f / (d2v + 1e-8f);
        float ws = w0 + w1 + w2;
        sWts[lane][0] = w0 / ws; sWts[lane][1] = w1 / ws; sWts[lane][2] = w2 / ws;
        sNbr[lane][0] = n0; sNbr[lane][1] = n1; sNbr[lane][2] = n2;
    }
    __syncthreads();
    for (int i = wv * 8; i < wv * 8 + 8; ++i) {
        float a0 = sWts[i][0], a1 = sWts[i][1], a2 = sWts[i][2];
        const float* r0 = fsub + (b * MM + sNbr[i][0]) * 128;
        const float* r1 = fsub + (b * MM + sNbr[i][1]) * 128;
        const float* r2 = fsub + (b * MM + sNbr[i][2]) * 128;
        float v0 = fmaf(a2, r2[lane], fmaf(a1, r1[lane], a0 * r0[lane]));
        float v1 = fmaf(a2, r2[64 + lane], fmaf(a1, r1[64 + lane], a0 * r0[64 + lane]));
        int row = b * NN + pbase + i;
        itp[row * 128 + lane] = v0;
        itp[row * 128 + 64 + lane] = v1;
    }
}

// ---------------- K5: f = relu([interp, f0] @ W_fp + b_fp) ----------------
__global__ __launch_bounds__(256) void k_fp(const float* __restrict__ itp,
                                            const float* __restrict__ f0,
                                            const float* __restrict__ W,
                                            const float* __restrict__ bias,
                                            float* __restrict__ outf) {
    __shared__ float sW[192 * 64];
    for (int i = threadIdx.x; i < 192 * 64; i += 256) sW[i] = W[i];
    __syncthreads();
    int lane = threadIdx.x & 63;
    int wv = threadIdx.x >> 6;
    float bb = bias[lane];
    int rowbase = blockIdx.x * 64 + wv * 16;
    for (int it = 0; it < 4; ++it) {
        int r = rowbase + it * 4;
        float fa[4], fbv[4], fc[4], acc[4];
        #pragma unroll
        for (int u = 0; u < 4; ++u) {
            fa[u]  = itp[(r + u) * 128 + lane];
            fbv[u] = itp[(r + u) * 128 + 64 + lane];
            fc[u]  = f0[(r + u) * 64 + lane];
            acc[u] = bb;
        }
        #pragma unroll
        for (int k = 0; k < 192; ++k) {
            float w = sW[k * 64 + lane];
            #pragma unroll
            for (int u = 0; u < 4; ++u) {
                float fv = k < 64 ? rl(fa[u], k)
                         : (k < 128 ? rl(fbv[u], k - 64) : rl(fc[u], k - 128));
                acc[u] = fmaf(fv, w, acc[u]);
            }
        }
        #pragma unroll
        for (int u = 0; u < 4; ++u)
            outf[(r + u) * 64 + lane] = fmaxf(acc[u], 0.f);
    }
}

// ---------------- K6: zc = [f, ef] @ W_fin + b_fin ----------------
__global__ __launch_bounds__(256) void k_fin(const float* __restrict__ fb,
                                             const float* __restrict__ efb,
                                             const float* __restrict__ W,
                                             const float* __restrict__ bias,
                                             float* __restrict__ zc) {
    __shared__ float sW[68 * 64];
    for (int i = threadIdx.x; i < 68 * 64; i += 256) sW[i] = W[i];
    __syncthreads();
    int lane = threadIdx.x & 63;
    int wv = threadIdx.x >> 6;
    float bb = bias[lane];
    int rowbase = blockIdx.x * 64 + wv * 16;
    for (int it = 0; it < 4; ++it) {
        int r = rowbase + it * 4;
        float fa[4], fe[4], acc[4];
        #pragma unroll
        for (int u = 0; u < 4; ++u) {
            fa[u] = fb[(r + u) * 64 + lane];
            fe[u] = (lane < 4) ? efb[(r + u) * 4 + lane] : 0.f;
            acc[u] = bb;
        }
        #pragma unroll
        for (int k = 0; k < 68; ++k) {
            float w = sW[k * 64 + lane];
            #pragma unroll
            for (int u = 0; u < 4; ++u) {
                float fv = k < 64 ? rl(fa[u], k) : rl(fe[u], k - 64);
                acc[u] = fmaf(fv, w, acc[u]);
            }
        }
        #pragma unroll
        for (int u = 0; u < 4; ++u)
            zc[(r + u) * 64 + lane] = acc[u];
    }
}

// ---------------- K7: batchnorm stats, two-stage ----------------
__global__ __launch_bounds__(256) void k_stats1(const float* __restrict__ zc,
                                                float* __restrict__ pp) {
    int t = threadIdx.x;
    int c = t & 63, r4 = t >> 6;
    float s = 0.f, sq = 0.f;
    int base = blockIdx.x * 512;
    for (int i = 0; i < 128; ++i) {
        float v = zc[(base + i * 4 + r4) * 64 + c];
        s += v;
        sq = fmaf(v, v, sq);
    }
    __shared__ float ls[256], lq[256];
    ls[t] = s; lq[t] = sq;
    __syncthreads();
    if (t < 64) {
        float st = ls[t] + ls[t + 64] + ls[t + 128] + ls[t + 192];
        float qt = lq[t] + lq[t + 64] + lq[t + 128] + lq[t + 192];
        pp[blockIdx.x * 128 + t] = st;
        pp[blockIdx.x * 128 + 64 + t] = qt;
    }
}

__global__ __launch_bounds__(64) void k_stats2(const float* __restrict__ pp,
                                               const float* __restrict__ gamma,
                                               const float* __restrict__ beta,
                                               float* __restrict__ ss) {
    int c = threadIdx.x;
    float s = 0.f, sq = 0.f;
    for (int k = 0; k < 64; ++k) {
        s += pp[k * 128 + c];
        sq += pp[k * 128 + 64 + c];
    }
    const float inv = 1.f / (float)(BB * NN);
    float mu = s * inv;
    float var = sq * inv - mu * mu;
    float sc = gamma[c] / sqrtf(var + 1e-5f);
    ss[c] = sc;
    ss[64 + c] = beta[c] - mu * sc;
}

// ---------------- K8: normalize + relu + transpose ----------------
__global__ __launch_bounds__(256) void k_norm_t(const float* __restrict__ zc,
                                                const float* __restrict__ ss,
                                                float* __restrict__ out) {
    __shared__ float sT[64][65];
    int blk = blockIdx.x;
    int b = blk >> 6;
    int nbase = (blk & 63) * 64;
    int c = threadIdx.x & 63;
    int r4 = threadIdx.x >> 6;
    float sc = ss[c], sh = ss[64 + c];
    #pragma unroll
    for (int i = 0; i < 16; ++i) {
        int nr = i * 4 + r4;
        float v = zc[(b * NN + nbase + nr) * 64 + c];
        sT[nr][c] = fmaxf(fmaf(v, sc, sh), 0.f);
    }
    __syncthreads();
    int nn = threadIdx.x & 63;
    #pragma unroll
    for (int i = 0; i < 16; ++i) {
        int cc = i * 4 + r4;
        out[BB * NN * 3 + (b * 64 + cc) * NN + nbase + nn] = sT[nn][cc];
    }
}

extern "C" void kernel_launch(void* const* d_in, const int* in_sizes, int n_in,
                              void* d_out, int out_size, void* d_ws, size_t ws_size,
                              hipStream_t stream) {
    const float* data = (const float*)d_in[0];
    const float* Wst  = (const float*)d_in[2];
    const float* bst  = (const float*)d_in[3];
    const float* Wsa  = (const float*)d_in[4];
    const float* bsa  = (const float*)d_in[5];
    const float* Wfp  = (const float*)d_in[6];
    const float* bfp  = (const float*)d_in[7];
    const float* We1  = (const float*)d_in[8];
    const float* be1  = (const float*)d_in[9];
    const float* We2  = (const float*)d_in[10];
    const float* be2  = (const float*)d_in[11];
    const float* Wfin = (const float*)d_in[12];
    const float* bfin = (const float*)d_in[13];
    const float* gamma = (const float*)d_in[14];
    const float* beta  = (const float*)d_in[15];
    float* out = (float*)d_out;

    // layout (floats): buffers consumed late come last so scratch can alias them
    float* f0   = (float*)d_ws;            // 2,097,152
    float* fsub = f0 + 2097152;            // 1,398,784
    float* efb  = fsub + 1398784;          //   131,072
    float* zc   = efb + 131072;            // 2,097,152
    float* ss   = zc + 2097152;            //       128
    float* pp   = ss + 128;                //     8,192
    float4* cand4 = (float4*)(pp + 8192);  //   131,072 floats, 16B-aligned
    uint32_t* mrgb = (uint32_t*)((float*)cand4 + 131072);   // 1,310,720 u32 region
    float* itp  = (float*)mrgb + 1310720;  // 4,194,304
    float* fb   = itp + 4194304;           // 2,097,152
    // sort scratch (cand4s 131,072 + perm 32,768 + gbox 4,096 words) aliases itp:
    // fully consumed by k_knn before k_interp writes itp.
    float4*   cand4s = (float4*)itp;
    uint32_t* perm   = (uint32_t*)(itp + 131072);
    float4*   gbox   = (float4*)(itp + 131072 + 32768);

    // stem grid: 8192 stem blocks + 128 prep blocks (block-level split)
    k_stem<<<(BB * NN * 64) / 256 + (BB * NN) / 256, 256, 0, stream>>>(
        data, Wst, bst, f0, out, cand4);
    k_sort<<<BB, 256, 0, stream>>>(cand4, cand4s, perm, gbox);
    k_knn<<<BB * NGRP, 512, 0, stream>>>(cand4s, perm, gbox, mrgb);
    k_knn_eig<<<(BB * NN) / 256, 256, 0, stream>>>(cand4, mrgb, We1, be1, We2, be2, efb);
    k_sa<<<(BB * MM + 3) / 4, 256, 0, stream>>>(cand4, data, f0, mrgb, Wsa, bsa, fsub);
    k_interp<<<BB * 64, 512, 0, stream>>>(cand4, fsub, itp);
    k_fp<<<512, 256, 0, stream>>>(itp, f0, Wfp, bfp, fb);
    k_fin<<<512, 256, 0, stream>>>(fb, efb, Wfin, bfin, zc);
    k_stats1<<<64, 256, 0, stream>>>(zc, pp);
    k_stats2<<<1, 64, 0, stream>>>(pp, gamma, beta, ss);
    k_norm_t<<<512, 256, 0, stream>>>(zc, ss, out);
}